// Round 5
// baseline (704.397 us; speedup 1.0000x reference)
//
#include <hip/hip_runtime.h>
#include <hip/hip_bf16.h>

// BGraphAttentionLayer: fused GAT layer, never materializes the 8192^2 attention.
// hp1 = E @ (Wh2/Z2), hp2 = E^T @ (Wh1/Z1), E = adj>0 ? exp(lrelu(s1_i+s2_j)) : 0.
// adj enters only via sign -> one 256MB sweep builds an 8MB bitmask + Z1/Z2;
// the two MFMA sweeps recompute E from (mask, s1, s2) with ~zero HBM traffic.

#define N 8192
#define FIN 256
#define FOUT 64

typedef float f32x4 __attribute__((ext_vector_type(4)));
typedef short s16x8 __attribute__((ext_vector_type(8)));
typedef unsigned short u16;
typedef unsigned long long u64;

__device__ __forceinline__ u16 f2bf(float x) {
  unsigned u = __builtin_bit_cast(unsigned, x);
  return (u16)((u + 0x7FFFu + ((u >> 16) & 1u)) >> 16);  // RTNE
}
__device__ __forceinline__ u16 f2bf_t(float x) {  // truncating (cheap)
  return (u16)(__builtin_bit_cast(unsigned, x) >> 16);
}
__device__ __forceinline__ float lrexp(float x) {
  return __expf(fmaxf(x, 0.2f * x));  // exp(leaky_relu(x, 0.2))
}

// ---------------- K1: Wh1/Wh2 (transposed, f32) + s1/s2 ----------------
__global__ __launch_bounds__(256) void k_prep(
    const float* __restrict__ h1, const float* __restrict__ h2,
    const float* __restrict__ W1, const float* __restrict__ W2,
    const float* __restrict__ a,
    float* __restrict__ Wh1T, float* __restrict__ Wh2T,
    float* __restrict__ s1, float* __restrict__ s2) {
  __shared__ float hbuf[16][FIN];
  const int t = threadIdx.x;
  const int r0 = blockIdx.x * 16;
  const int f = t & 63, q = t >> 6;
  const int lrow = t >> 4, lc0 = (t & 15) * 16;
  for (int mat = 0; mat < 2; ++mat) {
    const float* h = mat ? h2 : h1;
    const float* W = mat ? W2 : W1;
    float* WhT = mat ? Wh2T : Wh1T;
    float* so = mat ? s2 : s1;
    const float av = a[mat * FOUT + f];
    __syncthreads();
    const float* src = h + (size_t)(r0 + lrow) * FIN + lc0;
#pragma unroll
    for (int u = 0; u < 4; ++u)
      *(f32x4*)&hbuf[lrow][lc0 + u * 4] = *(const f32x4*)(src + u * 4);
    __syncthreads();
    float acc[4] = {0.f, 0.f, 0.f, 0.f};
    for (int k = 0; k < FIN; ++k) {
      float wv = W[k * FOUT + f];
#pragma unroll
      for (int rg = 0; rg < 4; ++rg)
        acc[rg] = fmaf(hbuf[rg * 4 + q][k], wv, acc[rg]);
    }
#pragma unroll
    for (int rg = 0; rg < 4; ++rg) {
      int r = r0 + rg * 4 + q;
      WhT[(size_t)f * N + r] = acc[rg];
      float sp = acc[rg] * av;
#pragma unroll
      for (int m = 1; m < 64; m <<= 1) sp += __shfl_xor(sp, m, 64);
      if (f == 0) so[r] = sp;
    }
  }
}

// ------- K2: one adj sweep -> Z1 (row sums), Z2 (col sums), bitmask -------
// grid (2 j-stripes of 4096, 1024 i-chunks of 8); thread owns 16 consecutive j.
// Lambda-free, statically-indexed arrays only; 2-row pipeline; row-sums kept
// in registers and reduced once at the end (no per-row shuffle chains).
__global__ __launch_bounds__(256, 2) void k_statsmask(
    const float* __restrict__ adj, const float* __restrict__ s1,
    const float* __restrict__ s2, float* __restrict__ Z1,
    float* __restrict__ Z2, u16* __restrict__ mask) {
  const int t = threadIdx.x;
  const int c0 = blockIdx.x * 4096 + t * 16;
  const int r0 = blockIdx.y * 8;
  const int wv = t >> 6, lane = t & 63;
  __shared__ float rowpart[4][8];
  f32x4 s2v[4];
#pragma unroll
  for (int q = 0; q < 4; ++q) s2v[q] = *(const f32x4*)(s2 + c0 + q * 4);
  f32x4 ca[4];
#pragma unroll
  for (int q = 0; q < 4; ++q) ca[q] = f32x4{0.f, 0.f, 0.f, 0.f};
  float rs[8];
  f32x4 v[2][4];
#pragma unroll
  for (int q = 0; q < 4; ++q)
    v[0][q] = *(const f32x4*)(adj + (size_t)r0 * N + c0 + q * 4);

#pragma unroll
  for (int r = 0; r < 8; ++r) {
    const int cur = r & 1;  // compile-time after unroll
    if (r + 1 < 8) {
#pragma unroll
      for (int q = 0; q < 4; ++q)
        v[cur ^ 1][q] =
            *(const f32x4*)(adj + (size_t)(r0 + r + 1) * N + c0 + q * 4);
    }
    const float s1v = s1[r0 + r];
    unsigned m = 0;
    float rsv = 0.f;
#pragma unroll
    for (int q = 0; q < 4; ++q)
#pragma unroll
      for (int c = 0; c < 4; ++c) {
        float ev = lrexp(s1v + s2v[q][c]);
        const bool on = v[cur][q][c] > 0.f;
        ev = on ? ev : 0.f;
        m |= (on ? 1u : 0u) << (q * 4 + c);
        ca[q][c] += ev;
        rsv += ev;
      }
    mask[(size_t)(r0 + r) * 512 + (c0 >> 4)] = (u16)m;
    rs[r] = rsv;
  }
  // reduce the 8 row partials across the wave, once
#pragma unroll
  for (int r = 0; r < 8; ++r) {
    float x = rs[r];
#pragma unroll
    for (int sh = 1; sh < 64; sh <<= 1) x += __shfl_xor(x, sh, 64);
    if (lane == 0) rowpart[wv][r] = x;
  }
  __syncthreads();
  if (t < 8)
    atomicAdd(&Z1[r0 + t],
              rowpart[0][t] + rowpart[1][t] + rowpart[2][t] + rowpart[3][t]);
#pragma unroll
  for (int q = 0; q < 4; ++q)
#pragma unroll
    for (int c = 0; c < 4; ++c) atomicAdd(&Z2[c0 + q * 4 + c], ca[q][c]);
}

// ---------------- K3: V{1,2}T = (Wh/Z)^T in bf16 ----------------
__global__ __launch_bounds__(256) void k_buildv(
    const float* __restrict__ Wh1T, const float* __restrict__ Wh2T,
    const float* __restrict__ Z1, const float* __restrict__ Z2,
    u16* __restrict__ V1T, u16* __restrict__ V2T) {
  const int mat = blockIdx.y;
  const float* WhT = mat ? Wh2T : Wh1T;
  const float* Z = mat ? Z2 : Z1;
  u16* VT = mat ? V2T : V1T;
  const int idx = (blockIdx.x * 256 + threadIdx.x) * 4;
  const int i = idx & (N - 1);
  f32x4 wh = *(const f32x4*)(WhT + idx);
  f32x4 z = *(const f32x4*)(Z + i);
  unsigned lo = (unsigned)f2bf(wh.x / z.x) | ((unsigned)f2bf(wh.y / z.y) << 16);
  unsigned hi = (unsigned)f2bf(wh.z / z.z) | ((unsigned)f2bf(wh.w / z.w) << 16);
  uint2 uv; uv.x = lo; uv.y = hi;
  *(uint2*)(VT + idx) = uv;
}

// -------- K4a: hp1 += E @ V2. Barrier-free, LDS-free, mask-driven. --------
// grid (64 i-chunks of 128, 16 j-strips of 512). Wave owns 32 rows.
__global__ __launch_bounds__(256, 2) void k_hp1(
    const u16* __restrict__ maskp, const float* __restrict__ s1g,
    const float* __restrict__ s2g, const u16* __restrict__ V2T,
    float* __restrict__ hp1) {
  const int t = threadIdx.x, w = t >> 6, lane = t & 63;
  const int l15 = lane & 15, l4 = lane >> 4;
  const int sh0 = l4 * 8;
  const int i0 = blockIdx.x * 128 + w * 32;
  const int jbase = blockIdx.y * 512;
  const u64* mrow0 = (const u64*)maskp + (size_t)(i0 + l15) * 128;
  const u64* mrow1 = mrow0 + 16 * 128;
  const float s1v0 = s1g[i0 + l15];
  const float s1v1 = s1g[i0 + 16 + l15];
  f32x4 acc[2][4];
#pragma unroll
  for (int mt = 0; mt < 2; ++mt)
#pragma unroll
    for (int nt = 0; nt < 4; ++nt) acc[mt][nt] = f32x4{0.f, 0.f, 0.f, 0.f};

#pragma unroll 2
  for (int js = 0; js < 8; ++js) {
    const int j0s = jbase + js * 64;
    const u64 m0 = mrow0[j0s >> 6];
    const u64 m1 = mrow1[j0s >> 6];
    f32x4 s2q[4];  // [kk*2+h]: s2[j0s + kk*32 + sh0 + h*4 ..]
#pragma unroll
    for (int kk = 0; kk < 2; ++kk)
#pragma unroll
      for (int h = 0; h < 2; ++h)
        s2q[kk * 2 + h] = *(const f32x4*)(s2g + j0s + kk * 32 + sh0 + h * 4);
    s16x8 bf[2][4];
#pragma unroll
    for (int kk = 0; kk < 2; ++kk)
#pragma unroll
      for (int nt = 0; nt < 4; ++nt)
        bf[kk][nt] = *(const s16x8*)(V2T + (size_t)(nt * 16 + l15) * N + j0s +
                                     kk * 32 + sh0);
    s16x8 afr[2][2];  // [mt][kk]
#pragma unroll
    for (int kk = 0; kk < 2; ++kk) {
      const unsigned b0 = (unsigned)(kk ? (m0 >> 32) : m0);
      const unsigned b1 = (unsigned)(kk ? (m1 >> 32) : m1);
#pragma unroll
      for (int e = 0; e < 8; ++e) {
        const float s2e = s2q[kk * 2 + (e >> 2)][e & 3];
        float e0 = lrexp(s1v0 + s2e);
        float e1 = lrexp(s1v1 + s2e);
        e0 = ((b0 >> (sh0 + e)) & 1u) ? e0 : 0.f;
        e1 = ((b1 >> (sh0 + e)) & 1u) ? e1 : 0.f;
        afr[0][kk][e] = (short)f2bf_t(e0);
        afr[1][kk][e] = (short)f2bf_t(e1);
      }
    }
#pragma unroll
    for (int nt = 0; nt < 4; ++nt) {
      acc[0][nt] = __builtin_amdgcn_mfma_f32_16x16x32_bf16(afr[0][0], bf[0][nt],
                                                           acc[0][nt], 0, 0, 0);
      acc[0][nt] = __builtin_amdgcn_mfma_f32_16x16x32_bf16(afr[0][1], bf[1][nt],
                                                           acc[0][nt], 0, 0, 0);
      acc[1][nt] = __builtin_amdgcn_mfma_f32_16x16x32_bf16(afr[1][0], bf[0][nt],
                                                           acc[1][nt], 0, 0, 0);
      acc[1][nt] = __builtin_amdgcn_mfma_f32_16x16x32_bf16(afr[1][1], bf[1][nt],
                                                           acc[1][nt], 0, 0, 0);
    }
  }
#pragma unroll
  for (int mt = 0; mt < 2; ++mt)
#pragma unroll
    for (int nt = 0; nt < 4; ++nt)
#pragma unroll
      for (int r = 0; r < 4; ++r)
        atomicAdd(&hp1[(size_t)(i0 + mt * 16 + l4 * 4 + r) * 64 + nt * 16 + l15],
                  acc[mt][nt][r]);
}

// -------- K4b: hp2 += E^T @ V1. Barrier-free, LDS-free, mask-driven. --------
// grid (64 j-chunks of 128, 16 i-strips of 512 = 8 tiles of 64). Wave owns 32 j.
__global__ __launch_bounds__(256, 2) void k_hp2(
    const u16* __restrict__ maskp, const float* __restrict__ s1g,
    const float* __restrict__ s2g, const u16* __restrict__ V1T,
    float* __restrict__ hp2) {
  const int t = threadIdx.x, w = t >> 6, lane = t & 63;
  const int l15 = lane & 15, l4 = lane >> 4;
  const int sh0 = l4 * 8;
  const int j0w = blockIdx.x * 128 + w * 32;
  const int ibase = blockIdx.y * 512;
  const float s2vA = s2g[j0w + l15];
  const float s2vB = s2g[j0w + 16 + l15];
  const unsigned* mask32 = (const unsigned*)maskp;
  const int wsel = j0w >> 5;  // u32 index within a 256-word row
  f32x4 acc[2][4];
#pragma unroll
  for (int mt = 0; mt < 2; ++mt)
#pragma unroll
    for (int nt = 0; nt < 4; ++nt) acc[mt][nt] = f32x4{0.f, 0.f, 0.f, 0.f};

#pragma unroll 2
  for (int tile = 0; tile < 8; ++tile) {
    const int it0 = ibase + tile * 64;
    f32x4 s1q[4];
#pragma unroll
    for (int kk = 0; kk < 2; ++kk)
#pragma unroll
      for (int h = 0; h < 2; ++h)
        s1q[kk * 2 + h] = *(const f32x4*)(s1g + it0 + kk * 32 + sh0 + h * 4);
    unsigned mw[2][8];
#pragma unroll
    for (int kk = 0; kk < 2; ++kk)
#pragma unroll
      for (int e = 0; e < 8; ++e)
        mw[kk][e] = mask32[(size_t)(it0 + kk * 32 + sh0 + e) * 256 + wsel];
    s16x8 bf[2][4];
#pragma unroll
    for (int kk = 0; kk < 2; ++kk)
#pragma unroll
      for (int nt = 0; nt < 4; ++nt)
        bf[kk][nt] = *(const s16x8*)(V1T + (size_t)(nt * 16 + l15) * N + it0 +
                                     kk * 32 + sh0);
    s16x8 aA[2], aB[2];  // [kk] for mt=0 / mt=1
#pragma unroll
    for (int kk = 0; kk < 2; ++kk)
#pragma unroll
      for (int e = 0; e < 8; ++e) {
        const float s1v = s1q[kk * 2 + (e >> 2)][e & 3];
        float eA = lrexp(s1v + s2vA);
        float eB = lrexp(s1v + s2vB);
        const unsigned mwv = mw[kk][e];
        eA = ((mwv >> l15) & 1u) ? eA : 0.f;
        eB = ((mwv >> (16 + l15)) & 1u) ? eB : 0.f;
        aA[kk][e] = (short)f2bf_t(eA);
        aB[kk][e] = (short)f2bf_t(eB);
      }
#pragma unroll
    for (int nt = 0; nt < 4; ++nt) {
      acc[0][nt] = __builtin_amdgcn_mfma_f32_16x16x32_bf16(aA[0], bf[0][nt],
                                                           acc[0][nt], 0, 0, 0);
      acc[0][nt] = __builtin_amdgcn_mfma_f32_16x16x32_bf16(aA[1], bf[1][nt],
                                                           acc[0][nt], 0, 0, 0);
      acc[1][nt] = __builtin_amdgcn_mfma_f32_16x16x32_bf16(aB[0], bf[0][nt],
                                                           acc[1][nt], 0, 0, 0);
      acc[1][nt] = __builtin_amdgcn_mfma_f32_16x16x32_bf16(aB[1], bf[1][nt],
                                                           acc[1][nt], 0, 0, 0);
    }
  }
#pragma unroll
  for (int mt = 0; mt < 2; ++mt)
#pragma unroll
    for (int nt = 0; nt < 4; ++nt)
#pragma unroll
      for (int r = 0; r < 4; ++r)
        atomicAdd(
            &hp2[(size_t)(j0w + mt * 16 + l4 * 4 + r) * 64 + nt * 16 + l15],
            acc[mt][nt][r]);
}

// ---------------- K5: ELU epilogue for both outputs ----------------
__global__ __launch_bounds__(256) void k_red(const float* __restrict__ hp1,
                                             const float* __restrict__ hp2,
                                             float* __restrict__ out) {
  const size_t idx = ((size_t)blockIdx.x * 256 + threadIdx.x) * 4;
  f32x4 v1 = *(const f32x4*)(hp1 + idx);
  f32x4 v2 = *(const f32x4*)(hp2 + idx);
  f32x4 o1, o2;
#pragma unroll
  for (int c = 0; c < 4; ++c) {
    o1[c] = v1[c] > 0.f ? v1[c] : expm1f(v1[c]);
    o2[c] = v2[c] > 0.f ? v2[c] : expm1f(v2[c]);
  }
  *(f32x4*)(out + idx) = o1;
  *(f32x4*)(out + (size_t)N * FOUT + idx) = o2;
}

extern "C" void kernel_launch(void* const* d_in, const int* in_sizes, int n_in,
                              void* d_out, int out_size, void* d_ws,
                              size_t ws_size, hipStream_t stream) {
  const float* h1 = (const float*)d_in[0];
  const float* h2 = (const float*)d_in[1];
  const float* adj = (const float*)d_in[2];
  const float* W1 = (const float*)d_in[3];
  const float* W2 = (const float*)d_in[4];
  const float* a = (const float*)d_in[5];

  float* ws = (float*)d_ws;
  // float-offset workspace layout (~19 MB total)
  float* s1 = ws + 0;
  float* s2 = ws + 8192;
  float* Z1 = ws + 16384;
  float* Z2 = ws + 24576;
  float* Wh1T = ws + 32768;               // [64][8192] f32
  float* Wh2T = ws + 557056;
  u16* V1T = (u16*)(ws + 1081344);        // [64][8192] bf16
  u16* V2T = V1T + 524288;
  u16* mask = (u16*)(ws + 1605632);       // [8192][512] u16 = 8 MB bitmask
  float* hp1 = ws + 3702784;              // [8192][64] f32
  float* hp2 = ws + 4227072;              // ends 4751360 floats

  hipMemsetAsync(Z1, 0, 2 * 8192 * sizeof(float), stream);               // Z1+Z2
  hipMemsetAsync(hp1, 0, 2 * (size_t)N * FOUT * sizeof(float), stream);  // hp1+hp2

  k_prep<<<512, 256, 0, stream>>>(h1, h2, W1, W2, a, Wh1T, Wh2T, s1, s2);
  k_statsmask<<<dim3(2, 1024), 256, 0, stream>>>(adj, s1, s2, Z1, Z2, mask);
  k_buildv<<<dim3(512, 2), 256, 0, stream>>>(Wh1T, Wh2T, Z1, Z2, V1T, V2T);
  k_hp1<<<dim3(64, 16), 256, 0, stream>>>(mask, s1, s2, V2T, hp1);
  k_hp2<<<dim3(64, 16), 256, 0, stream>>>(mask, s1, s2, V1T, hp2);
  k_red<<<512, 256, 0, stream>>>(hp1, hp2, (float*)d_out);
}

// Round 6
// 540.668 us; speedup vs baseline: 1.3028x; 1.3028x over previous
//
#include <hip/hip_runtime.h>
#include <hip/hip_bf16.h>

// BGraphAttentionLayer: fused GAT layer, never materializes the 8192^2 attention.
// hp1 = E @ (Wh2/Z2), hp2 = E^T @ (Wh1/Z1), E = adj>0 ? exp(lrelu(s1_i+s2_j)) : 0.
// adj enters only via sign -> one 256MB sweep builds an 8MB bitmask + Z1/Z2;
// the two MFMA sweeps recompute E from (mask, s1, s2) with ~zero HBM traffic.

#define N 8192
#define FIN 256
#define FOUT 64

typedef float f32x4 __attribute__((ext_vector_type(4)));
typedef short s16x8 __attribute__((ext_vector_type(8)));
typedef unsigned short u16;
typedef unsigned long long u64;

__device__ __forceinline__ u16 f2bf(float x) {
  unsigned u = __builtin_bit_cast(unsigned, x);
  return (u16)((u + 0x7FFFu + ((u >> 16) & 1u)) >> 16);  // RTNE
}
__device__ __forceinline__ u16 f2bf_t(float x) {  // truncating (cheap)
  return (u16)(__builtin_bit_cast(unsigned, x) >> 16);
}
__device__ __forceinline__ float lrexp(float x) {
  return __expf(fmaxf(x, 0.2f * x));  // exp(leaky_relu(x, 0.2))
}

// ---------------- K1: Wh1/Wh2 (transposed, f32) + s1/s2 ----------------
__global__ __launch_bounds__(256) void k_prep(
    const float* __restrict__ h1, const float* __restrict__ h2,
    const float* __restrict__ W1, const float* __restrict__ W2,
    const float* __restrict__ a,
    float* __restrict__ Wh1T, float* __restrict__ Wh2T,
    float* __restrict__ s1, float* __restrict__ s2) {
  __shared__ float hbuf[16][FIN];
  const int t = threadIdx.x;
  const int r0 = blockIdx.x * 16;
  const int f = t & 63, q = t >> 6;
  const int lrow = t >> 4, lc0 = (t & 15) * 16;
  for (int mat = 0; mat < 2; ++mat) {
    const float* h = mat ? h2 : h1;
    const float* W = mat ? W2 : W1;
    float* WhT = mat ? Wh2T : Wh1T;
    float* so = mat ? s2 : s1;
    const float av = a[mat * FOUT + f];
    __syncthreads();
    const float* src = h + (size_t)(r0 + lrow) * FIN + lc0;
#pragma unroll
    for (int u = 0; u < 4; ++u)
      *(f32x4*)&hbuf[lrow][lc0 + u * 4] = *(const f32x4*)(src + u * 4);
    __syncthreads();
    float acc[4] = {0.f, 0.f, 0.f, 0.f};
    for (int k = 0; k < FIN; ++k) {
      float wv = W[k * FOUT + f];
#pragma unroll
      for (int rg = 0; rg < 4; ++rg)
        acc[rg] = fmaf(hbuf[rg * 4 + q][k], wv, acc[rg]);
    }
#pragma unroll
    for (int rg = 0; rg < 4; ++rg) {
      int r = r0 + rg * 4 + q;
      WhT[(size_t)f * N + r] = acc[rg];
      float sp = acc[rg] * av;
#pragma unroll
      for (int m = 1; m < 64; m <<= 1) sp += __shfl_xor(sp, m, 64);
      if (f == 0) so[r] = sp;
    }
  }
}

// ------- K2: one adj sweep -> Z1 (row sums), Z2 (col sums), bitmask -------
// grid (2 j-stripes of 4096, 512 i-chunks of 16); thread owns 16 consecutive j.
// ALL values are named SSA registers -- no arrays (rule #20: indexed arrays
// in this kernel went to scratch in r4/r5, costing 264MB of spill traffic).
__global__ __launch_bounds__(256) void k_statsmask(
    const float* __restrict__ adj, const float* __restrict__ s1,
    const float* __restrict__ s2, float* __restrict__ Z1,
    float* __restrict__ Z2, u16* __restrict__ mask) {
  const int t = threadIdx.x;
  const int c0 = blockIdx.x * 4096 + t * 16;
  const int r0 = blockIdx.y * 16;
  const int wv = t >> 6, lane = t & 63;
  __shared__ float rowpart[4][16];
  const f32x4 s2a = *(const f32x4*)(s2 + c0);
  const f32x4 s2b = *(const f32x4*)(s2 + c0 + 4);
  const f32x4 s2c = *(const f32x4*)(s2 + c0 + 8);
  const f32x4 s2d = *(const f32x4*)(s2 + c0 + 12);
  f32x4 ca = f32x4{0.f, 0.f, 0.f, 0.f};
  f32x4 cb = f32x4{0.f, 0.f, 0.f, 0.f};
  f32x4 cc = f32x4{0.f, 0.f, 0.f, 0.f};
  f32x4 cd = f32x4{0.f, 0.f, 0.f, 0.f};
  u16* mrow = mask + (size_t)r0 * 512 + (c0 >> 4);
#pragma unroll
  for (int r = 0; r < 16; ++r) {
    const float* rowp = adj + (size_t)(r0 + r) * N + c0;
    const f32x4 a = *(const f32x4*)(rowp);
    const f32x4 b = *(const f32x4*)(rowp + 4);
    const f32x4 c = *(const f32x4*)(rowp + 8);
    const f32x4 d = *(const f32x4*)(rowp + 12);
    const float s1v = s1[r0 + r];
    unsigned m = 0;
    float rsv = 0.f;
#pragma unroll
    for (int e = 0; e < 4; ++e) {
      float ev = lrexp(s1v + s2a[e]);
      ev = (a[e] > 0.f) ? ev : 0.f;
      m |= (a[e] > 0.f ? 1u : 0u) << e;
      ca[e] += ev; rsv += ev;
    }
#pragma unroll
    for (int e = 0; e < 4; ++e) {
      float ev = lrexp(s1v + s2b[e]);
      ev = (b[e] > 0.f) ? ev : 0.f;
      m |= (b[e] > 0.f ? 1u : 0u) << (4 + e);
      cb[e] += ev; rsv += ev;
    }
#pragma unroll
    for (int e = 0; e < 4; ++e) {
      float ev = lrexp(s1v + s2c[e]);
      ev = (c[e] > 0.f) ? ev : 0.f;
      m |= (c[e] > 0.f ? 1u : 0u) << (8 + e);
      cc[e] += ev; rsv += ev;
    }
#pragma unroll
    for (int e = 0; e < 4; ++e) {
      float ev = lrexp(s1v + s2d[e]);
      ev = (d[e] > 0.f) ? ev : 0.f;
      m |= (d[e] > 0.f ? 1u : 0u) << (12 + e);
      cd[e] += ev; rsv += ev;
    }
    mrow[(size_t)r * 512] = (u16)m;
#pragma unroll
    for (int sh = 1; sh < 64; sh <<= 1) rsv += __shfl_xor(rsv, sh, 64);
    if (lane == 0) rowpart[wv][r] = rsv;
  }
  __syncthreads();
  if (t < 16)
    atomicAdd(&Z1[r0 + t],
              rowpart[0][t] + rowpart[1][t] + rowpart[2][t] + rowpart[3][t]);
#pragma unroll
  for (int e = 0; e < 4; ++e) atomicAdd(&Z2[c0 + e], ca[e]);
#pragma unroll
  for (int e = 0; e < 4; ++e) atomicAdd(&Z2[c0 + 4 + e], cb[e]);
#pragma unroll
  for (int e = 0; e < 4; ++e) atomicAdd(&Z2[c0 + 8 + e], cc[e]);
#pragma unroll
  for (int e = 0; e < 4; ++e) atomicAdd(&Z2[c0 + 12 + e], cd[e]);
}

// ---------------- K3: V{1,2}T = (Wh/Z)^T in bf16 ----------------
__global__ __launch_bounds__(256) void k_buildv(
    const float* __restrict__ Wh1T, const float* __restrict__ Wh2T,
    const float* __restrict__ Z1, const float* __restrict__ Z2,
    u16* __restrict__ V1T, u16* __restrict__ V2T) {
  const int mat = blockIdx.y;
  const float* WhT = mat ? Wh2T : Wh1T;
  const float* Z = mat ? Z2 : Z1;
  u16* VT = mat ? V2T : V1T;
  const int idx = (blockIdx.x * 256 + threadIdx.x) * 4;
  const int i = idx & (N - 1);
  f32x4 wh = *(const f32x4*)(WhT + idx);
  f32x4 z = *(const f32x4*)(Z + i);
  unsigned lo = (unsigned)f2bf(wh.x / z.x) | ((unsigned)f2bf(wh.y / z.y) << 16);
  unsigned hi = (unsigned)f2bf(wh.z / z.z) | ((unsigned)f2bf(wh.w / z.w) << 16);
  uint2 uv; uv.x = lo; uv.y = hi;
  *(uint2*)(VT + idx) = uv;
}

// -------- K4a: hp1 += E @ V2. Barrier-free, LDS-free, mask-driven. --------
// grid (64 i-chunks of 128, 16 j-strips of 512). Wave owns 32 rows.
__global__ __launch_bounds__(256, 2) void k_hp1(
    const u16* __restrict__ maskp, const float* __restrict__ s1g,
    const float* __restrict__ s2g, const u16* __restrict__ V2T,
    float* __restrict__ hp1) {
  const int t = threadIdx.x, w = t >> 6, lane = t & 63;
  const int l15 = lane & 15, l4 = lane >> 4;
  const int sh0 = l4 * 8;
  const int i0 = blockIdx.x * 128 + w * 32;
  const int jbase = blockIdx.y * 512;
  const u64* mrow0 = (const u64*)maskp + (size_t)(i0 + l15) * 128;
  const u64* mrow1 = mrow0 + 16 * 128;
  const float s1v0 = s1g[i0 + l15];
  const float s1v1 = s1g[i0 + 16 + l15];
  f32x4 acc[2][4];
#pragma unroll
  for (int mt = 0; mt < 2; ++mt)
#pragma unroll
    for (int nt = 0; nt < 4; ++nt) acc[mt][nt] = f32x4{0.f, 0.f, 0.f, 0.f};

#pragma unroll 2
  for (int js = 0; js < 8; ++js) {
    const int j0s = jbase + js * 64;
    const u64 m0 = mrow0[j0s >> 6];
    const u64 m1 = mrow1[j0s >> 6];
    f32x4 s2q[4];  // [kk*2+h]: s2[j0s + kk*32 + sh0 + h*4 ..]
#pragma unroll
    for (int kk = 0; kk < 2; ++kk)
#pragma unroll
      for (int h = 0; h < 2; ++h)
        s2q[kk * 2 + h] = *(const f32x4*)(s2g + j0s + kk * 32 + sh0 + h * 4);
    s16x8 bf[2][4];
#pragma unroll
    for (int kk = 0; kk < 2; ++kk)
#pragma unroll
      for (int nt = 0; nt < 4; ++nt)
        bf[kk][nt] = *(const s16x8*)(V2T + (size_t)(nt * 16 + l15) * N + j0s +
                                     kk * 32 + sh0);
    s16x8 afr[2][2];  // [mt][kk]
#pragma unroll
    for (int kk = 0; kk < 2; ++kk) {
      const unsigned b0 = (unsigned)(kk ? (m0 >> 32) : m0);
      const unsigned b1 = (unsigned)(kk ? (m1 >> 32) : m1);
#pragma unroll
      for (int e = 0; e < 8; ++e) {
        const float s2e = s2q[kk * 2 + (e >> 2)][e & 3];
        float e0 = lrexp(s1v0 + s2e);
        float e1 = lrexp(s1v1 + s2e);
        e0 = ((b0 >> (sh0 + e)) & 1u) ? e0 : 0.f;
        e1 = ((b1 >> (sh0 + e)) & 1u) ? e1 : 0.f;
        afr[0][kk][e] = (short)f2bf_t(e0);
        afr[1][kk][e] = (short)f2bf_t(e1);
      }
    }
#pragma unroll
    for (int nt = 0; nt < 4; ++nt) {
      acc[0][nt] = __builtin_amdgcn_mfma_f32_16x16x32_bf16(afr[0][0], bf[0][nt],
                                                           acc[0][nt], 0, 0, 0);
      acc[0][nt] = __builtin_amdgcn_mfma_f32_16x16x32_bf16(afr[0][1], bf[1][nt],
                                                           acc[0][nt], 0, 0, 0);
      acc[1][nt] = __builtin_amdgcn_mfma_f32_16x16x32_bf16(afr[1][0], bf[0][nt],
                                                           acc[1][nt], 0, 0, 0);
      acc[1][nt] = __builtin_amdgcn_mfma_f32_16x16x32_bf16(afr[1][1], bf[1][nt],
                                                           acc[1][nt], 0, 0, 0);
    }
  }
#pragma unroll
  for (int mt = 0; mt < 2; ++mt)
#pragma unroll
    for (int nt = 0; nt < 4; ++nt)
#pragma unroll
      for (int r = 0; r < 4; ++r)
        atomicAdd(&hp1[(size_t)(i0 + mt * 16 + l4 * 4 + r) * 64 + nt * 16 + l15],
                  acc[mt][nt][r]);
}

// -------- K4b: hp2 += E^T @ V1. Barrier-free, LDS-free, mask-driven. --------
// grid (64 j-chunks of 128, 16 i-strips of 512 = 8 tiles of 64). Wave owns 32 j.
__global__ __launch_bounds__(256, 2) void k_hp2(
    const u16* __restrict__ maskp, const float* __restrict__ s1g,
    const float* __restrict__ s2g, const u16* __restrict__ V1T,
    float* __restrict__ hp2) {
  const int t = threadIdx.x, w = t >> 6, lane = t & 63;
  const int l15 = lane & 15, l4 = lane >> 4;
  const int sh0 = l4 * 8;
  const int j0w = blockIdx.x * 128 + w * 32;
  const int ibase = blockIdx.y * 512;
  const float s2vA = s2g[j0w + l15];
  const float s2vB = s2g[j0w + 16 + l15];
  const unsigned* mask32 = (const unsigned*)maskp;
  const int wsel = j0w >> 5;  // u32 index within a 256-word row
  f32x4 acc[2][4];
#pragma unroll
  for (int mt = 0; mt < 2; ++mt)
#pragma unroll
    for (int nt = 0; nt < 4; ++nt) acc[mt][nt] = f32x4{0.f, 0.f, 0.f, 0.f};

#pragma unroll 2
  for (int tile = 0; tile < 8; ++tile) {
    const int it0 = ibase + tile * 64;
    f32x4 s1q[4];
#pragma unroll
    for (int kk = 0; kk < 2; ++kk)
#pragma unroll
      for (int h = 0; h < 2; ++h)
        s1q[kk * 2 + h] = *(const f32x4*)(s1g + it0 + kk * 32 + sh0 + h * 4);
    unsigned mw[2][8];
#pragma unroll
    for (int kk = 0; kk < 2; ++kk)
#pragma unroll
      for (int e = 0; e < 8; ++e)
        mw[kk][e] = mask32[(size_t)(it0 + kk * 32 + sh0 + e) * 256 + wsel];
    s16x8 bf[2][4];
#pragma unroll
    for (int kk = 0; kk < 2; ++kk)
#pragma unroll
      for (int nt = 0; nt < 4; ++nt)
        bf[kk][nt] = *(const s16x8*)(V1T + (size_t)(nt * 16 + l15) * N + it0 +
                                     kk * 32 + sh0);
    s16x8 aA[2], aB[2];  // [kk] for mt=0 / mt=1
#pragma unroll
    for (int kk = 0; kk < 2; ++kk)
#pragma unroll
      for (int e = 0; e < 8; ++e) {
        const float s1v = s1q[kk * 2 + (e >> 2)][e & 3];
        float eA = lrexp(s1v + s2vA);
        float eB = lrexp(s1v + s2vB);
        const unsigned mwv = mw[kk][e];
        eA = ((mwv >> l15) & 1u) ? eA : 0.f;
        eB = ((mwv >> (16 + l15)) & 1u) ? eB : 0.f;
        aA[kk][e] = (short)f2bf_t(eA);
        aB[kk][e] = (short)f2bf_t(eB);
      }
#pragma unroll
    for (int nt = 0; nt < 4; ++nt) {
      acc[0][nt] = __builtin_amdgcn_mfma_f32_16x16x32_bf16(aA[0], bf[0][nt],
                                                           acc[0][nt], 0, 0, 0);
      acc[0][nt] = __builtin_amdgcn_mfma_f32_16x16x32_bf16(aA[1], bf[1][nt],
                                                           acc[0][nt], 0, 0, 0);
      acc[1][nt] = __builtin_amdgcn_mfma_f32_16x16x32_bf16(aB[0], bf[0][nt],
                                                           acc[1][nt], 0, 0, 0);
      acc[1][nt] = __builtin_amdgcn_mfma_f32_16x16x32_bf16(aB[1], bf[1][nt],
                                                           acc[1][nt], 0, 0, 0);
    }
  }
#pragma unroll
  for (int mt = 0; mt < 2; ++mt)
#pragma unroll
    for (int nt = 0; nt < 4; ++nt)
#pragma unroll
      for (int r = 0; r < 4; ++r)
        atomicAdd(
            &hp2[(size_t)(j0w + mt * 16 + l4 * 4 + r) * 64 + nt * 16 + l15],
            acc[mt][nt][r]);
}

// ---------------- K5: ELU epilogue for both outputs ----------------
__global__ __launch_bounds__(256) void k_red(const float* __restrict__ hp1,
                                             const float* __restrict__ hp2,
                                             float* __restrict__ out) {
  const size_t idx = ((size_t)blockIdx.x * 256 + threadIdx.x) * 4;
  f32x4 v1 = *(const f32x4*)(hp1 + idx);
  f32x4 v2 = *(const f32x4*)(hp2 + idx);
  f32x4 o1, o2;
#pragma unroll
  for (int c = 0; c < 4; ++c) {
    o1[c] = v1[c] > 0.f ? v1[c] : expm1f(v1[c]);
    o2[c] = v2[c] > 0.f ? v2[c] : expm1f(v2[c]);
  }
  *(f32x4*)(out + idx) = o1;
  *(f32x4*)(out + (size_t)N * FOUT + idx) = o2;
}

extern "C" void kernel_launch(void* const* d_in, const int* in_sizes, int n_in,
                              void* d_out, int out_size, void* d_ws,
                              size_t ws_size, hipStream_t stream) {
  const float* h1 = (const float*)d_in[0];
  const float* h2 = (const float*)d_in[1];
  const float* adj = (const float*)d_in[2];
  const float* W1 = (const float*)d_in[3];
  const float* W2 = (const float*)d_in[4];
  const float* a = (const float*)d_in[5];

  float* ws = (float*)d_ws;
  // float-offset workspace layout (~19 MB total)
  float* s1 = ws + 0;
  float* s2 = ws + 8192;
  float* Z1 = ws + 16384;
  float* Z2 = ws + 24576;
  float* Wh1T = ws + 32768;               // [64][8192] f32
  float* Wh2T = ws + 557056;
  u16* V1T = (u16*)(ws + 1081344);        // [64][8192] bf16
  u16* V2T = V1T + 524288;
  u16* mask = (u16*)(ws + 1605632);       // [8192][512] u16 = 8 MB bitmask
  float* hp1 = ws + 3702784;              // [8192][64] f32
  float* hp2 = ws + 4227072;              // ends 4751360 floats

  hipMemsetAsync(Z1, 0, 2 * 8192 * sizeof(float), stream);               // Z1+Z2
  hipMemsetAsync(hp1, 0, 2 * (size_t)N * FOUT * sizeof(float), stream);  // hp1+hp2

  k_prep<<<512, 256, 0, stream>>>(h1, h2, W1, W2, a, Wh1T, Wh2T, s1, s2);
  k_statsmask<<<dim3(2, 512), 256, 0, stream>>>(adj, s1, s2, Z1, Z2, mask);
  k_buildv<<<dim3(512, 2), 256, 0, stream>>>(Wh1T, Wh2T, Z1, Z2, V1T, V2T);
  k_hp1<<<dim3(64, 16), 256, 0, stream>>>(mask, s1, s2, V2T, hp1);
  k_hp2<<<dim3(64, 16), 256, 0, stream>>>(mask, s1, s2, V1T, hp2);
  k_red<<<512, 256, 0, stream>>>(hp1, hp2, (float*)d_out);
}

// Round 7
// 429.511 us; speedup vs baseline: 1.6400x; 1.2588x over previous
//
#include <hip/hip_runtime.h>
#include <hip/hip_bf16.h>

// BGraphAttentionLayer: fused GAT layer, never materializes the 8192^2 attention.
// hp1 = E @ (Wh2/Z2), hp2 = E^T @ (Wh1/Z1), E = adj>0 ? exp(lrelu(s1_i+s2_j)) : 0.
// adj enters only via sign -> one 256MB sweep builds an 8MB bitmask + Z1/Z2;
// the two MFMA sweeps recompute E from (mask, s1, s2) with ~zero HBM traffic.

#define N 8192
#define FIN 256
#define FOUT 64

typedef float f32x4 __attribute__((ext_vector_type(4)));
typedef short s16x8 __attribute__((ext_vector_type(8)));
typedef unsigned short u16;
typedef unsigned long long u64;

__device__ __forceinline__ u16 f2bf(float x) {
  unsigned u = __builtin_bit_cast(unsigned, x);
  return (u16)((u + 0x7FFFu + ((u >> 16) & 1u)) >> 16);  // RTNE
}
__device__ __forceinline__ u16 f2bf_t(float x) {  // truncating (cheap)
  return (u16)(__builtin_bit_cast(unsigned, x) >> 16);
}
__device__ __forceinline__ float lrexp(float x) {
  return __expf(fmaxf(x, 0.2f * x));  // exp(leaky_relu(x, 0.2))
}

// ---------------- K1: Wh1/Wh2 (transposed, f32) + s1/s2 ----------------
__global__ __launch_bounds__(256) void k_prep(
    const float* __restrict__ h1, const float* __restrict__ h2,
    const float* __restrict__ W1, const float* __restrict__ W2,
    const float* __restrict__ a,
    float* __restrict__ Wh1T, float* __restrict__ Wh2T,
    float* __restrict__ s1, float* __restrict__ s2) {
  __shared__ float hbuf[16][FIN];
  const int t = threadIdx.x;
  const int r0 = blockIdx.x * 16;
  const int f = t & 63, q = t >> 6;
  const int lrow = t >> 4, lc0 = (t & 15) * 16;
  for (int mat = 0; mat < 2; ++mat) {
    const float* h = mat ? h2 : h1;
    const float* W = mat ? W2 : W1;
    float* WhT = mat ? Wh2T : Wh1T;
    float* so = mat ? s2 : s1;
    const float av = a[mat * FOUT + f];
    __syncthreads();
    const float* src = h + (size_t)(r0 + lrow) * FIN + lc0;
#pragma unroll
    for (int u = 0; u < 4; ++u)
      *(f32x4*)&hbuf[lrow][lc0 + u * 4] = *(const f32x4*)(src + u * 4);
    __syncthreads();
    float acc[4] = {0.f, 0.f, 0.f, 0.f};
    for (int k = 0; k < FIN; ++k) {
      float wv = W[k * FOUT + f];
#pragma unroll
      for (int rg = 0; rg < 4; ++rg)
        acc[rg] = fmaf(hbuf[rg * 4 + q][k], wv, acc[rg]);
    }
#pragma unroll
    for (int rg = 0; rg < 4; ++rg) {
      int r = r0 + rg * 4 + q;
      WhT[(size_t)f * N + r] = acc[rg];
      float sp = acc[rg] * av;
#pragma unroll
      for (int m = 1; m < 64; m <<= 1) sp += __shfl_xor(sp, m, 64);
      if (f == 0) so[r] = sp;
    }
  }
}

// ------- K2: one adj sweep -> Z1 (row sums), Z2 (col sums), bitmask -------
// grid (2 j-stripes of 4096, 512 i-chunks of 16); thread owns 16 consecutive j.
// unroll-1 row loop + explicit 2-row pipeline with NAMED registers only.
// (r4/r5/r6 all died to scratch spill: arrays / lambdas / full-unroll load
// hoisting. Keep the live set bounded and let TLP hide latency.)

#define PROC_ROW(rr, Av, Bv, Cv, Dv)                                       \
  {                                                                        \
    const float s1v = s1[r0 + (rr)];                                       \
    unsigned m = 0;                                                        \
    float rsv = 0.f;                                                       \
    _Pragma("unroll") for (int e = 0; e < 4; ++e) {                        \
      float ev = lrexp(s1v + s2a[e]);                                      \
      const bool on = Av[e] > 0.f;                                         \
      ev = on ? ev : 0.f;                                                  \
      m |= (on ? 1u : 0u) << e;                                            \
      ca[e] += ev; rsv += ev;                                              \
    }                                                                      \
    _Pragma("unroll") for (int e = 0; e < 4; ++e) {                        \
      float ev = lrexp(s1v + s2b[e]);                                      \
      const bool on = Bv[e] > 0.f;                                         \
      ev = on ? ev : 0.f;                                                  \
      m |= (on ? 1u : 0u) << (4 + e);                                      \
      cb[e] += ev; rsv += ev;                                              \
    }                                                                      \
    _Pragma("unroll") for (int e = 0; e < 4; ++e) {                        \
      float ev = lrexp(s1v + s2c[e]);                                      \
      const bool on = Cv[e] > 0.f;                                         \
      ev = on ? ev : 0.f;                                                  \
      m |= (on ? 1u : 0u) << (8 + e);                                      \
      cc[e] += ev; rsv += ev;                                              \
    }                                                                      \
    _Pragma("unroll") for (int e = 0; e < 4; ++e) {                        \
      float ev = lrexp(s1v + s2d[e]);                                      \
      const bool on = Dv[e] > 0.f;                                         \
      ev = on ? ev : 0.f;                                                  \
      m |= (on ? 1u : 0u) << (12 + e);                                     \
      cd[e] += ev; rsv += ev;                                              \
    }                                                                      \
    mask[(size_t)(r0 + (rr)) * 512 + mcol] = (u16)m;                       \
    _Pragma("unroll") for (int sh = 1; sh < 64; sh <<= 1)                  \
        rsv += __shfl_xor(rsv, sh, 64);                                    \
    if (lane == 0) atomicAdd(&Z1[r0 + (rr)], rsv);                         \
  }

__global__ __launch_bounds__(256) void k_statsmask(
    const float* __restrict__ adj, const float* __restrict__ s1,
    const float* __restrict__ s2, float* __restrict__ Z1,
    float* __restrict__ Z2, u16* __restrict__ mask) {
  const int t = threadIdx.x;
  const int col0 = blockIdx.x * 4096 + t * 16;
  const int r0 = blockIdx.y * 16;
  const int lane = t & 63;
  const int mcol = blockIdx.x * 256 + t;
  const f32x4 s2a = *(const f32x4*)(s2 + col0);
  const f32x4 s2b = *(const f32x4*)(s2 + col0 + 4);
  const f32x4 s2c = *(const f32x4*)(s2 + col0 + 8);
  const f32x4 s2d = *(const f32x4*)(s2 + col0 + 12);
  f32x4 ca = f32x4{0.f, 0.f, 0.f, 0.f};
  f32x4 cb = f32x4{0.f, 0.f, 0.f, 0.f};
  f32x4 cc = f32x4{0.f, 0.f, 0.f, 0.f};
  f32x4 cd = f32x4{0.f, 0.f, 0.f, 0.f};
  const float* base = adj + col0;

  // prologue: row 0 into bank0
  f32x4 A0 = *(const f32x4*)(base + (size_t)r0 * N);
  f32x4 B0 = *(const f32x4*)(base + (size_t)r0 * N + 4);
  f32x4 C0 = *(const f32x4*)(base + (size_t)r0 * N + 8);
  f32x4 D0 = *(const f32x4*)(base + (size_t)r0 * N + 12);
  f32x4 A1, B1, C1, D1;

#pragma unroll 1
  for (int r = 0; r < 16; r += 2) {
    const size_t ro1 = (size_t)(r0 + r + 1) * N;
    A1 = *(const f32x4*)(base + ro1);
    B1 = *(const f32x4*)(base + ro1 + 4);
    C1 = *(const f32x4*)(base + ro1 + 8);
    D1 = *(const f32x4*)(base + ro1 + 12);
    PROC_ROW(r, A0, B0, C0, D0);
    const int rn = (r + 2 < 16) ? (r + 2) : 0;  // last iter: dummy reload row 0
    const size_t ro2 = (size_t)(r0 + rn) * N;
    A0 = *(const f32x4*)(base + ro2);
    B0 = *(const f32x4*)(base + ro2 + 4);
    C0 = *(const f32x4*)(base + ro2 + 8);
    D0 = *(const f32x4*)(base + ro2 + 12);
    PROC_ROW(r + 1, A1, B1, C1, D1);
  }
#pragma unroll
  for (int e = 0; e < 4; ++e) atomicAdd(&Z2[col0 + e], ca[e]);
#pragma unroll
  for (int e = 0; e < 4; ++e) atomicAdd(&Z2[col0 + 4 + e], cb[e]);
#pragma unroll
  for (int e = 0; e < 4; ++e) atomicAdd(&Z2[col0 + 8 + e], cc[e]);
#pragma unroll
  for (int e = 0; e < 4; ++e) atomicAdd(&Z2[col0 + 12 + e], cd[e]);
}

// ---------------- K3: V{1,2}T = (Wh/Z)^T in bf16 ----------------
__global__ __launch_bounds__(256) void k_buildv(
    const float* __restrict__ Wh1T, const float* __restrict__ Wh2T,
    const float* __restrict__ Z1, const float* __restrict__ Z2,
    u16* __restrict__ V1T, u16* __restrict__ V2T) {
  const int mat = blockIdx.y;
  const float* WhT = mat ? Wh2T : Wh1T;
  const float* Z = mat ? Z2 : Z1;
  u16* VT = mat ? V2T : V1T;
  const int idx = (blockIdx.x * 256 + threadIdx.x) * 4;
  const int i = idx & (N - 1);
  f32x4 wh = *(const f32x4*)(WhT + idx);
  f32x4 z = *(const f32x4*)(Z + i);
  unsigned lo = (unsigned)f2bf(wh.x / z.x) | ((unsigned)f2bf(wh.y / z.y) << 16);
  unsigned hi = (unsigned)f2bf(wh.z / z.z) | ((unsigned)f2bf(wh.w / z.w) << 16);
  uint2 uv; uv.x = lo; uv.y = hi;
  *(uint2*)(VT + idx) = uv;
}

// -------- K4a: hp1 += E @ V2. Barrier-free, LDS-free, mask-driven. --------
// grid (64 i-chunks of 128, 16 j-strips of 512). Wave owns 32 rows.
__global__ __launch_bounds__(256, 2) void k_hp1(
    const u16* __restrict__ maskp, const float* __restrict__ s1g,
    const float* __restrict__ s2g, const u16* __restrict__ V2T,
    float* __restrict__ hp1) {
  const int t = threadIdx.x, w = t >> 6, lane = t & 63;
  const int l15 = lane & 15, l4 = lane >> 4;
  const int sh0 = l4 * 8;
  const int i0 = blockIdx.x * 128 + w * 32;
  const int jbase = blockIdx.y * 512;
  const u64* mrow0 = (const u64*)maskp + (size_t)(i0 + l15) * 128;
  const u64* mrow1 = mrow0 + 16 * 128;
  const float s1v0 = s1g[i0 + l15];
  const float s1v1 = s1g[i0 + 16 + l15];
  f32x4 acc[2][4];
#pragma unroll
  for (int mt = 0; mt < 2; ++mt)
#pragma unroll
    for (int nt = 0; nt < 4; ++nt) acc[mt][nt] = f32x4{0.f, 0.f, 0.f, 0.f};

#pragma unroll 2
  for (int js = 0; js < 8; ++js) {
    const int j0s = jbase + js * 64;
    const u64 m0 = mrow0[j0s >> 6];
    const u64 m1 = mrow1[j0s >> 6];
    f32x4 s2q[4];  // [kk*2+h]: s2[j0s + kk*32 + sh0 + h*4 ..]
#pragma unroll
    for (int kk = 0; kk < 2; ++kk)
#pragma unroll
      for (int h = 0; h < 2; ++h)
        s2q[kk * 2 + h] = *(const f32x4*)(s2g + j0s + kk * 32 + sh0 + h * 4);
    s16x8 bf[2][4];
#pragma unroll
    for (int kk = 0; kk < 2; ++kk)
#pragma unroll
      for (int nt = 0; nt < 4; ++nt)
        bf[kk][nt] = *(const s16x8*)(V2T + (size_t)(nt * 16 + l15) * N + j0s +
                                     kk * 32 + sh0);
    s16x8 afr[2][2];  // [mt][kk]
#pragma unroll
    for (int kk = 0; kk < 2; ++kk) {
      const unsigned b0 = (unsigned)(kk ? (m0 >> 32) : m0);
      const unsigned b1 = (unsigned)(kk ? (m1 >> 32) : m1);
#pragma unroll
      for (int e = 0; e < 8; ++e) {
        const float s2e = s2q[kk * 2 + (e >> 2)][e & 3];
        float e0 = lrexp(s1v0 + s2e);
        float e1 = lrexp(s1v1 + s2e);
        e0 = ((b0 >> (sh0 + e)) & 1u) ? e0 : 0.f;
        e1 = ((b1 >> (sh0 + e)) & 1u) ? e1 : 0.f;
        afr[0][kk][e] = (short)f2bf_t(e0);
        afr[1][kk][e] = (short)f2bf_t(e1);
      }
    }
#pragma unroll
    for (int nt = 0; nt < 4; ++nt) {
      acc[0][nt] = __builtin_amdgcn_mfma_f32_16x16x32_bf16(afr[0][0], bf[0][nt],
                                                           acc[0][nt], 0, 0, 0);
      acc[0][nt] = __builtin_amdgcn_mfma_f32_16x16x32_bf16(afr[0][1], bf[1][nt],
                                                           acc[0][nt], 0, 0, 0);
      acc[1][nt] = __builtin_amdgcn_mfma_f32_16x16x32_bf16(afr[1][0], bf[0][nt],
                                                           acc[1][nt], 0, 0, 0);
      acc[1][nt] = __builtin_amdgcn_mfma_f32_16x16x32_bf16(afr[1][1], bf[1][nt],
                                                           acc[1][nt], 0, 0, 0);
    }
  }
#pragma unroll
  for (int mt = 0; mt < 2; ++mt)
#pragma unroll
    for (int nt = 0; nt < 4; ++nt)
#pragma unroll
      for (int r = 0; r < 4; ++r)
        atomicAdd(&hp1[(size_t)(i0 + mt * 16 + l4 * 4 + r) * 64 + nt * 16 + l15],
                  acc[mt][nt][r]);
}

// -------- K4b: hp2 += E^T @ V1. Barrier-free, LDS-free, mask-driven. --------
// grid (64 j-chunks of 128, 16 i-strips of 512 = 8 tiles of 64). Wave owns 32 j.
__global__ __launch_bounds__(256, 2) void k_hp2(
    const u16* __restrict__ maskp, const float* __restrict__ s1g,
    const float* __restrict__ s2g, const u16* __restrict__ V1T,
    float* __restrict__ hp2) {
  const int t = threadIdx.x, w = t >> 6, lane = t & 63;
  const int l15 = lane & 15, l4 = lane >> 4;
  const int sh0 = l4 * 8;
  const int j0w = blockIdx.x * 128 + w * 32;
  const int ibase = blockIdx.y * 512;
  const float s2vA = s2g[j0w + l15];
  const float s2vB = s2g[j0w + 16 + l15];
  const unsigned* mask32 = (const unsigned*)maskp;
  const int wsel = j0w >> 5;  // u32 index within a 256-word row
  f32x4 acc[2][4];
#pragma unroll
  for (int mt = 0; mt < 2; ++mt)
#pragma unroll
    for (int nt = 0; nt < 4; ++nt) acc[mt][nt] = f32x4{0.f, 0.f, 0.f, 0.f};

#pragma unroll 2
  for (int tile = 0; tile < 8; ++tile) {
    const int it0 = ibase + tile * 64;
    f32x4 s1q[4];
#pragma unroll
    for (int kk = 0; kk < 2; ++kk)
#pragma unroll
      for (int h = 0; h < 2; ++h)
        s1q[kk * 2 + h] = *(const f32x4*)(s1g + it0 + kk * 32 + sh0 + h * 4);
    unsigned mw[2][8];
#pragma unroll
    for (int kk = 0; kk < 2; ++kk)
#pragma unroll
      for (int e = 0; e < 8; ++e)
        mw[kk][e] = mask32[(size_t)(it0 + kk * 32 + sh0 + e) * 256 + wsel];
    s16x8 bf[2][4];
#pragma unroll
    for (int kk = 0; kk < 2; ++kk)
#pragma unroll
      for (int nt = 0; nt < 4; ++nt)
        bf[kk][nt] = *(const s16x8*)(V1T + (size_t)(nt * 16 + l15) * N + it0 +
                                     kk * 32 + sh0);
    s16x8 aA[2], aB[2];  // [kk] for mt=0 / mt=1
#pragma unroll
    for (int kk = 0; kk < 2; ++kk)
#pragma unroll
      for (int e = 0; e < 8; ++e) {
        const float s1v = s1q[kk * 2 + (e >> 2)][e & 3];
        float eA = lrexp(s1v + s2vA);
        float eB = lrexp(s1v + s2vB);
        const unsigned mwv = mw[kk][e];
        eA = ((mwv >> l15) & 1u) ? eA : 0.f;
        eB = ((mwv >> (16 + l15)) & 1u) ? eB : 0.f;
        aA[kk][e] = (short)f2bf_t(eA);
        aB[kk][e] = (short)f2bf_t(eB);
      }
#pragma unroll
    for (int nt = 0; nt < 4; ++nt) {
      acc[0][nt] = __builtin_amdgcn_mfma_f32_16x16x32_bf16(aA[0], bf[0][nt],
                                                           acc[0][nt], 0, 0, 0);
      acc[0][nt] = __builtin_amdgcn_mfma_f32_16x16x32_bf16(aA[1], bf[1][nt],
                                                           acc[0][nt], 0, 0, 0);
      acc[1][nt] = __builtin_amdgcn_mfma_f32_16x16x32_bf16(aB[0], bf[0][nt],
                                                           acc[1][nt], 0, 0, 0);
      acc[1][nt] = __builtin_amdgcn_mfma_f32_16x16x32_bf16(aB[1], bf[1][nt],
                                                           acc[1][nt], 0, 0, 0);
    }
  }
#pragma unroll
  for (int mt = 0; mt < 2; ++mt)
#pragma unroll
    for (int nt = 0; nt < 4; ++nt)
#pragma unroll
      for (int r = 0; r < 4; ++r)
        atomicAdd(
            &hp2[(size_t)(j0w + mt * 16 + l4 * 4 + r) * 64 + nt * 16 + l15],
            acc[mt][nt][r]);
}

// ---------------- K5: ELU epilogue for both outputs ----------------
__global__ __launch_bounds__(256) void k_red(const float* __restrict__ hp1,
                                             const float* __restrict__ hp2,
                                             float* __restrict__ out) {
  const size_t idx = ((size_t)blockIdx.x * 256 + threadIdx.x) * 4;
  f32x4 v1 = *(const f32x4*)(hp1 + idx);
  f32x4 v2 = *(const f32x4*)(hp2 + idx);
  f32x4 o1, o2;
#pragma unroll
  for (int c = 0; c < 4; ++c) {
    o1[c] = v1[c] > 0.f ? v1[c] : expm1f(v1[c]);
    o2[c] = v2[c] > 0.f ? v2[c] : expm1f(v2[c]);
  }
  *(f32x4*)(out + idx) = o1;
  *(f32x4*)(out + (size_t)N * FOUT + idx) = o2;
}

extern "C" void kernel_launch(void* const* d_in, const int* in_sizes, int n_in,
                              void* d_out, int out_size, void* d_ws,
                              size_t ws_size, hipStream_t stream) {
  const float* h1 = (const float*)d_in[0];
  const float* h2 = (const float*)d_in[1];
  const float* adj = (const float*)d_in[2];
  const float* W1 = (const float*)d_in[3];
  const float* W2 = (const float*)d_in[4];
  const float* a = (const float*)d_in[5];

  float* ws = (float*)d_ws;
  // float-offset workspace layout (~19 MB total)
  float* s1 = ws + 0;
  float* s2 = ws + 8192;
  float* Z1 = ws + 16384;
  float* Z2 = ws + 24576;
  float* Wh1T = ws + 32768;               // [64][8192] f32
  float* Wh2T = ws + 557056;
  u16* V1T = (u16*)(ws + 1081344);        // [64][8192] bf16
  u16* V2T = V1T + 524288;
  u16* mask = (u16*)(ws + 1605632);       // [8192][512] u16 = 8 MB bitmask
  float* hp1 = ws + 3702784;              // [8192][64] f32
  float* hp2 = ws + 4227072;              // ends 4751360 floats

  hipMemsetAsync(Z1, 0, 2 * 8192 * sizeof(float), stream);               // Z1+Z2
  hipMemsetAsync(hp1, 0, 2 * (size_t)N * FOUT * sizeof(float), stream);  // hp1+hp2

  k_prep<<<512, 256, 0, stream>>>(h1, h2, W1, W2, a, Wh1T, Wh2T, s1, s2);
  k_statsmask<<<dim3(2, 512), 256, 0, stream>>>(adj, s1, s2, Z1, Z2, mask);
  k_buildv<<<dim3(512, 2), 256, 0, stream>>>(Wh1T, Wh2T, Z1, Z2, V1T, V2T);
  k_hp1<<<dim3(64, 16), 256, 0, stream>>>(mask, s1, s2, V2T, hp1);
  k_hp2<<<dim3(64, 16), 256, 0, stream>>>(mask, s1, s2, V1T, hp2);
  k_red<<<512, 256, 0, stream>>>(hp1, hp2, (float*)d_out);
}

// Round 8
// 366.804 us; speedup vs baseline: 1.9204x; 1.1710x over previous
//
#include <hip/hip_runtime.h>
#include <hip/hip_bf16.h>

// BGraphAttentionLayer: fused GAT layer, never materializes the 8192^2 attention.
// hp1 = E @ (Wh2/Z2), hp2 = E^T @ (Wh1/Z1), E = adj>0 ? exp(lrelu(s1_i+s2_j)) : 0.
// adj enters only via sign -> one pure-streaming sweep builds an 8MB bitmask;
// Z1/Z2 and the two MFMA sweeps recompute E from (mask, s1, s2): mask is
// L3-resident, so everything after the sweep is ~HBM-free.
// s1/s2 are pre-scaled by log2(e) so E-gen uses exp2 (one VALU op less/elem).

#define N 8192
#define FIN 256
#define FOUT 64

typedef float f32x4 __attribute__((ext_vector_type(4)));
typedef short s16x8 __attribute__((ext_vector_type(8)));
typedef unsigned short u16;
typedef unsigned long long u64;

__device__ __forceinline__ u16 f2bf(float x) {
  unsigned u = __builtin_bit_cast(unsigned, x);
  return (u16)((u + 0x7FFFu + ((u >> 16) & 1u)) >> 16);  // RTNE
}
__device__ __forceinline__ u16 f2bf_t(float x) {  // truncating (cheap)
  return (u16)(__builtin_bit_cast(unsigned, x) >> 16);
}
// x is already scaled by log2(e): exp(lrelu(y)) == exp2(max(x, 0.2x))
__device__ __forceinline__ float lrexp2(float x) {
  return exp2f(fmaxf(x, 0.2f * x));
}

// ------- K1: Wh1/Wh2 (transposed, f32) + s1/s2 (pre-scaled) + zero-init -------
__global__ __launch_bounds__(256) void k_prep(
    const float* __restrict__ h1, const float* __restrict__ h2,
    const float* __restrict__ W1, const float* __restrict__ W2,
    const float* __restrict__ a,
    float* __restrict__ Wh1T, float* __restrict__ Wh2T,
    float* __restrict__ s1, float* __restrict__ s2,
    float* __restrict__ hpz, float* __restrict__ Z2z) {
  __shared__ float hbuf[16][FIN];
  const int t = threadIdx.x;
  const int r0 = blockIdx.x * 16;
  const int f = t & 63, q = t >> 6;
  const int lrow = t >> 4, lc0 = (t & 15) * 16;
  // zero hp1+hp2 (contiguous 1M floats) and Z2 -- replaces hipMemsetAsync
  {
    const int g = blockIdx.x * 256 + t;
    const f32x4 zz = f32x4{0.f, 0.f, 0.f, 0.f};
    *(f32x4*)(hpz + (size_t)g * 8) = zz;
    *(f32x4*)(hpz + (size_t)g * 8 + 4) = zz;
    if (g < 2048) *(f32x4*)(Z2z + g * 4) = zz;
  }
  for (int mat = 0; mat < 2; ++mat) {
    const float* h = mat ? h2 : h1;
    const float* W = mat ? W2 : W1;
    float* WhT = mat ? Wh2T : Wh1T;
    float* so = mat ? s2 : s1;
    const float av = a[mat * FOUT + f];
    __syncthreads();
    const float* src = h + (size_t)(r0 + lrow) * FIN + lc0;
#pragma unroll
    for (int u = 0; u < 4; ++u)
      *(f32x4*)&hbuf[lrow][lc0 + u * 4] = *(const f32x4*)(src + u * 4);
    __syncthreads();
    float acc[4] = {0.f, 0.f, 0.f, 0.f};
    for (int k = 0; k < FIN; ++k) {
      float wv = W[k * FOUT + f];
#pragma unroll
      for (int rg = 0; rg < 4; ++rg)
        acc[rg] = fmaf(hbuf[rg * 4 + q][k], wv, acc[rg]);
    }
#pragma unroll
    for (int rg = 0; rg < 4; ++rg) {
      int r = r0 + rg * 4 + q;
      WhT[(size_t)f * N + r] = acc[rg];
      float sp = acc[rg] * av;
#pragma unroll
      for (int m = 1; m < 64; m <<= 1) sp += __shfl_xor(sp, m, 64);
      if (f == 0) so[r] = sp * 1.4426950408889634f;  // fold log2(e)
    }
  }
}

// ---------------- K2: pure sign sweep -> bitmask (the only 256MB read) -------
// grid (2 col-stripes of 4096, 1024 row-chunks of 8); thread = 16 consecutive j.
__global__ __launch_bounds__(256) void k_mask(const float* __restrict__ adj,
                                              u16* __restrict__ mask) {
  const int t = threadIdx.x;
  const int col0 = blockIdx.x * 4096 + t * 16;
  const int r0 = blockIdx.y * 8;
  const int mcol = blockIdx.x * 256 + t;
  const float* base = adj + col0;
#pragma unroll 1
  for (int r = 0; r < 8; ++r) {
    const size_t ro = (size_t)(r0 + r) * N;
    const f32x4 a = *(const f32x4*)(base + ro);
    const f32x4 b = *(const f32x4*)(base + ro + 4);
    const f32x4 c = *(const f32x4*)(base + ro + 8);
    const f32x4 d = *(const f32x4*)(base + ro + 12);
    unsigned m = 0;
#pragma unroll
    for (int e = 0; e < 4; ++e) m |= (a[e] > 0.f ? 1u : 0u) << e;
#pragma unroll
    for (int e = 0; e < 4; ++e) m |= (b[e] > 0.f ? 1u : 0u) << (4 + e);
#pragma unroll
    for (int e = 0; e < 4; ++e) m |= (c[e] > 0.f ? 1u : 0u) << (8 + e);
#pragma unroll
    for (int e = 0; e < 4; ++e) m |= (d[e] > 0.f ? 1u : 0u) << (12 + e);
    mask[(size_t)(r0 + r) * 512 + mcol] = (u16)m;
  }
}

// ------- K2b: Z1 row sums from mask (block per row, no atomics) -------
__global__ __launch_bounds__(256) void k_z1(const u16* __restrict__ maskp,
                                            const float* __restrict__ s1,
                                            const float* __restrict__ s2,
                                            float* __restrict__ Z1) {
  const int row = blockIdx.x;
  const int t = threadIdx.x, lane = t & 63, wv = t >> 6;
  const u64* mrow = (const u64*)maskp + (size_t)row * 128;
  const float s1v = s1[row];
  __shared__ float part[4];
  float z = 0.f;
#pragma unroll 2
  for (int k = 0; k < 32; ++k) {
    const u64 word = mrow[wv + 4 * k];  // wave-uniform -> broadcast
    const float s2v = s2[t + 256 * k];  // coalesced
    const float ev = lrexp2(s1v + s2v);
    z += ((word >> lane) & 1ull) ? ev : 0.f;
  }
#pragma unroll
  for (int sh = 1; sh < 64; sh <<= 1) z += __shfl_xor(z, sh, 64);
  if (lane == 0) part[wv] = z;
  __syncthreads();
  if (t == 0) Z1[row] = part[0] + part[1] + part[2] + part[3];
}

// ------- K2c: Z2 col sums from mask (thread per col, strip atomics) -------
__global__ __launch_bounds__(256) void k_z2(const u16* __restrict__ maskp,
                                            const float* __restrict__ s1,
                                            const float* __restrict__ s2,
                                            float* __restrict__ Z2) {
  const int j = blockIdx.x * 256 + threadIdx.x;
  const int i0 = blockIdx.y * 512;
  const int lane = threadIdx.x & 63;
  const u64* m64 = (const u64*)maskp + (j >> 6);
  const float s2v = s2[j];
  float z = 0.f;
#pragma unroll 2
  for (int i = i0; i < i0 + 512; ++i) {
    const u64 word = m64[(size_t)i * 128];  // wave-uniform -> broadcast
    const float ev = lrexp2(s1[i] + s2v);
    z += ((word >> lane) & 1ull) ? ev : 0.f;
  }
  atomicAdd(&Z2[j], z);
}

// ---------------- K3: V{1,2}T = (Wh/Z)^T in bf16 ----------------
__global__ __launch_bounds__(256) void k_buildv(
    const float* __restrict__ Wh1T, const float* __restrict__ Wh2T,
    const float* __restrict__ Z1, const float* __restrict__ Z2,
    u16* __restrict__ V1T, u16* __restrict__ V2T) {
  const int mat = blockIdx.y;
  const float* WhT = mat ? Wh2T : Wh1T;
  const float* Z = mat ? Z2 : Z1;
  u16* VT = mat ? V2T : V1T;
  const int idx = (blockIdx.x * 256 + threadIdx.x) * 4;
  const int i = idx & (N - 1);
  f32x4 wh = *(const f32x4*)(WhT + idx);
  f32x4 z = *(const f32x4*)(Z + i);
  unsigned lo = (unsigned)f2bf(wh.x / z.x) | ((unsigned)f2bf(wh.y / z.y) << 16);
  unsigned hi = (unsigned)f2bf(wh.z / z.z) | ((unsigned)f2bf(wh.w / z.w) << 16);
  uint2 uv; uv.x = lo; uv.y = hi;
  *(uint2*)(VT + idx) = uv;
}

// -------- K4a: hp1 += E @ V2. Barrier-free, LDS-free, mask-driven. --------
// grid (64 i-chunks of 128, 32 j-strips of 256). Wave owns 32 rows.
__global__ __launch_bounds__(256, 2) void k_hp1(
    const u16* __restrict__ maskp, const float* __restrict__ s1g,
    const float* __restrict__ s2g, const u16* __restrict__ V2T,
    float* __restrict__ hp1) {
  const int t = threadIdx.x, w = t >> 6, lane = t & 63;
  const int l15 = lane & 15, l4 = lane >> 4;
  const int sh0 = l4 * 8;
  const int i0 = blockIdx.x * 128 + w * 32;
  const int jbase = blockIdx.y * 256;
  const u64* mrow0 = (const u64*)maskp + (size_t)(i0 + l15) * 128;
  const u64* mrow1 = mrow0 + 16 * 128;
  const float s1v0 = s1g[i0 + l15];
  const float s1v1 = s1g[i0 + 16 + l15];
  f32x4 acc[2][4];
#pragma unroll
  for (int mt = 0; mt < 2; ++mt)
#pragma unroll
    for (int nt = 0; nt < 4; ++nt) acc[mt][nt] = f32x4{0.f, 0.f, 0.f, 0.f};

#pragma unroll 2
  for (int js = 0; js < 4; ++js) {
    const int j0s = jbase + js * 64;
    const u64 m0 = mrow0[j0s >> 6];
    const u64 m1 = mrow1[j0s >> 6];
    f32x4 s2q[4];  // [kk*2+h]: s2[j0s + kk*32 + sh0 + h*4 ..]
#pragma unroll
    for (int kk = 0; kk < 2; ++kk)
#pragma unroll
      for (int h = 0; h < 2; ++h)
        s2q[kk * 2 + h] = *(const f32x4*)(s2g + j0s + kk * 32 + sh0 + h * 4);
    s16x8 bf[2][4];
#pragma unroll
    for (int kk = 0; kk < 2; ++kk)
#pragma unroll
      for (int nt = 0; nt < 4; ++nt)
        bf[kk][nt] = *(const s16x8*)(V2T + (size_t)(nt * 16 + l15) * N + j0s +
                                     kk * 32 + sh0);
    s16x8 afr[2][2];  // [mt][kk]
#pragma unroll
    for (int kk = 0; kk < 2; ++kk) {
      const unsigned b0 = (unsigned)(kk ? (m0 >> 32) : m0);
      const unsigned b1 = (unsigned)(kk ? (m1 >> 32) : m1);
#pragma unroll
      for (int e = 0; e < 8; ++e) {
        const float s2e = s2q[kk * 2 + (e >> 2)][e & 3];
        float e0 = lrexp2(s1v0 + s2e);
        float e1 = lrexp2(s1v1 + s2e);
        e0 = ((b0 >> (sh0 + e)) & 1u) ? e0 : 0.f;
        e1 = ((b1 >> (sh0 + e)) & 1u) ? e1 : 0.f;
        afr[0][kk][e] = (short)f2bf_t(e0);
        afr[1][kk][e] = (short)f2bf_t(e1);
      }
    }
#pragma unroll
    for (int nt = 0; nt < 4; ++nt) {
      acc[0][nt] = __builtin_amdgcn_mfma_f32_16x16x32_bf16(afr[0][0], bf[0][nt],
                                                           acc[0][nt], 0, 0, 0);
      acc[0][nt] = __builtin_amdgcn_mfma_f32_16x16x32_bf16(afr[0][1], bf[1][nt],
                                                           acc[0][nt], 0, 0, 0);
      acc[1][nt] = __builtin_amdgcn_mfma_f32_16x16x32_bf16(afr[1][0], bf[0][nt],
                                                           acc[1][nt], 0, 0, 0);
      acc[1][nt] = __builtin_amdgcn_mfma_f32_16x16x32_bf16(afr[1][1], bf[1][nt],
                                                           acc[1][nt], 0, 0, 0);
    }
  }
#pragma unroll
  for (int mt = 0; mt < 2; ++mt)
#pragma unroll
    for (int nt = 0; nt < 4; ++nt)
#pragma unroll
      for (int r = 0; r < 4; ++r)
        atomicAdd(&hp1[(size_t)(i0 + mt * 16 + l4 * 4 + r) * 64 + nt * 16 + l15],
                  acc[mt][nt][r]);
}

// -------- K4b: hp2 += E^T @ V1. Barrier-free, LDS-free, mask-driven. --------
// grid (64 j-chunks of 128, 32 i-strips of 256 = 4 tiles of 64). Wave owns 32 j.
__global__ __launch_bounds__(256, 2) void k_hp2(
    const u16* __restrict__ maskp, const float* __restrict__ s1g,
    const float* __restrict__ s2g, const u16* __restrict__ V1T,
    float* __restrict__ hp2) {
  const int t = threadIdx.x, w = t >> 6, lane = t & 63;
  const int l15 = lane & 15, l4 = lane >> 4;
  const int sh0 = l4 * 8;
  const int j0w = blockIdx.x * 128 + w * 32;
  const int ibase = blockIdx.y * 256;
  const float s2vA = s2g[j0w + l15];
  const float s2vB = s2g[j0w + 16 + l15];
  const unsigned* mask32 = (const unsigned*)maskp;
  const int wsel = j0w >> 5;  // u32 index within a 256-word row
  f32x4 acc[2][4];
#pragma unroll
  for (int mt = 0; mt < 2; ++mt)
#pragma unroll
    for (int nt = 0; nt < 4; ++nt) acc[mt][nt] = f32x4{0.f, 0.f, 0.f, 0.f};

#pragma unroll 2
  for (int tile = 0; tile < 4; ++tile) {
    const int it0 = ibase + tile * 64;
    f32x4 s1q[4];
#pragma unroll
    for (int kk = 0; kk < 2; ++kk)
#pragma unroll
      for (int h = 0; h < 2; ++h)
        s1q[kk * 2 + h] = *(const f32x4*)(s1g + it0 + kk * 32 + sh0 + h * 4);
    unsigned mw[2][8];
#pragma unroll
    for (int kk = 0; kk < 2; ++kk)
#pragma unroll
      for (int e = 0; e < 8; ++e)
        mw[kk][e] = mask32[(size_t)(it0 + kk * 32 + sh0 + e) * 256 + wsel];
    s16x8 bf[2][4];
#pragma unroll
    for (int kk = 0; kk < 2; ++kk)
#pragma unroll
      for (int nt = 0; nt < 4; ++nt)
        bf[kk][nt] = *(const s16x8*)(V1T + (size_t)(nt * 16 + l15) * N + it0 +
                                     kk * 32 + sh0);
    s16x8 aA[2], aB[2];  // [kk] for mt=0 / mt=1
#pragma unroll
    for (int kk = 0; kk < 2; ++kk)
#pragma unroll
      for (int e = 0; e < 8; ++e) {
        const float s1v = s1q[kk * 2 + (e >> 2)][e & 3];
        float eA = lrexp2(s1v + s2vA);
        float eB = lrexp2(s1v + s2vB);
        const unsigned mwv = mw[kk][e];
        eA = ((mwv >> l15) & 1u) ? eA : 0.f;
        eB = ((mwv >> (16 + l15)) & 1u) ? eB : 0.f;
        aA[kk][e] = (short)f2bf_t(eA);
        aB[kk][e] = (short)f2bf_t(eB);
      }
#pragma unroll
    for (int nt = 0; nt < 4; ++nt) {
      acc[0][nt] = __builtin_amdgcn_mfma_f32_16x16x32_bf16(aA[0], bf[0][nt],
                                                           acc[0][nt], 0, 0, 0);
      acc[0][nt] = __builtin_amdgcn_mfma_f32_16x16x32_bf16(aA[1], bf[1][nt],
                                                           acc[0][nt], 0, 0, 0);
      acc[1][nt] = __builtin_amdgcn_mfma_f32_16x16x32_bf16(aB[0], bf[0][nt],
                                                           acc[1][nt], 0, 0, 0);
      acc[1][nt] = __builtin_amdgcn_mfma_f32_16x16x32_bf16(aB[1], bf[1][nt],
                                                           acc[1][nt], 0, 0, 0);
    }
  }
#pragma unroll
  for (int mt = 0; mt < 2; ++mt)
#pragma unroll
    for (int nt = 0; nt < 4; ++nt)
#pragma unroll
      for (int r = 0; r < 4; ++r)
        atomicAdd(
            &hp2[(size_t)(j0w + mt * 16 + l4 * 4 + r) * 64 + nt * 16 + l15],
            acc[mt][nt][r]);
}

// ---------------- K5: ELU epilogue for both outputs ----------------
__global__ __launch_bounds__(256) void k_red(const float* __restrict__ hp1,
                                             const float* __restrict__ hp2,
                                             float* __restrict__ out) {
  const size_t idx = ((size_t)blockIdx.x * 256 + threadIdx.x) * 4;
  f32x4 v1 = *(const f32x4*)(hp1 + idx);
  f32x4 v2 = *(const f32x4*)(hp2 + idx);
  f32x4 o1, o2;
#pragma unroll
  for (int c = 0; c < 4; ++c) {
    o1[c] = v1[c] > 0.f ? v1[c] : expm1f(v1[c]);
    o2[c] = v2[c] > 0.f ? v2[c] : expm1f(v2[c]);
  }
  *(f32x4*)(out + idx) = o1;
  *(f32x4*)(out + (size_t)N * FOUT + idx) = o2;
}

extern "C" void kernel_launch(void* const* d_in, const int* in_sizes, int n_in,
                              void* d_out, int out_size, void* d_ws,
                              size_t ws_size, hipStream_t stream) {
  const float* h1 = (const float*)d_in[0];
  const float* h2 = (const float*)d_in[1];
  const float* adj = (const float*)d_in[2];
  const float* W1 = (const float*)d_in[3];
  const float* W2 = (const float*)d_in[4];
  const float* a = (const float*)d_in[5];

  float* ws = (float*)d_ws;
  // float-offset workspace layout (~19 MB total)
  float* s1 = ws + 0;
  float* s2 = ws + 8192;
  float* Z1 = ws + 16384;
  float* Z2 = ws + 24576;
  float* Wh1T = ws + 32768;               // [64][8192] f32
  float* Wh2T = ws + 557056;
  u16* V1T = (u16*)(ws + 1081344);        // [64][8192] bf16
  u16* V2T = V1T + 524288;
  u16* mask = (u16*)(ws + 1605632);       // [8192][512] u16 = 8 MB bitmask
  float* hp1 = ws + 3702784;              // [8192][64] f32
  float* hp2 = ws + 4227072;              // hp1+hp2 contiguous 1048576 floats

  k_prep<<<512, 256, 0, stream>>>(h1, h2, W1, W2, a, Wh1T, Wh2T, s1, s2, hp1,
                                  Z2);
  k_mask<<<dim3(2, 1024), 256, 0, stream>>>(adj, mask);
  k_z1<<<8192, 256, 0, stream>>>(mask, s1, s2, Z1);
  k_z2<<<dim3(32, 16), 256, 0, stream>>>(mask, s1, s2, Z2);
  k_buildv<<<dim3(512, 2), 256, 0, stream>>>(Wh1T, Wh2T, Z1, Z2, V1T, V2T);
  k_hp1<<<dim3(64, 32), 256, 0, stream>>>(mask, s1, s2, V2T, hp1);
  k_hp2<<<dim3(64, 32), 256, 0, stream>>>(mask, s1, s2, V1T, hp2);
  k_red<<<512, 256, 0, stream>>>(hp1, hp2, (float*)d_out);
}

// Round 9
// 329.590 us; speedup vs baseline: 2.1372x; 1.1129x over previous
//
#include <hip/hip_runtime.h>
#include <hip/hip_bf16.h>

// BGraphAttentionLayer: fused GAT layer, never materializes the 8192^2 attention.
// hp1 = E @ (Wh2/Z2), hp2 = E^T @ (Wh1/Z1), E = adj>0 ? exp(lrelu(s1_i+s2_j)) : 0.
// adj enters only via sign -> one pure-streaming coalesced sweep builds an 8MB
// bitmask; Z1/Z2 and the two MFMA sweeps recompute E from (mask, s1, s2).
// hp outputs via split-K partials (plain stores) + a strip-sum epilogue: the
// pipeline has no global atomics on any hot path.
// s1/s2 are pre-scaled by log2(e) so E-gen uses exp2.

#define N 8192
#define FIN 256
#define FOUT 64
#define NSTRIP 16
#define HPSZ ((size_t)N * FOUT)  // 524288 floats per partial strip

typedef float f32x4 __attribute__((ext_vector_type(4)));
typedef short s16x8 __attribute__((ext_vector_type(8)));
typedef unsigned short u16;
typedef unsigned long long u64;

__device__ __forceinline__ u16 f2bf(float x) {
  unsigned u = __builtin_bit_cast(unsigned, x);
  return (u16)((u + 0x7FFFu + ((u >> 16) & 1u)) >> 16);  // RTNE
}
__device__ __forceinline__ u16 f2bf_t(float x) {  // truncating (cheap)
  return (u16)(__builtin_bit_cast(unsigned, x) >> 16);
}
// x is already scaled by log2(e): exp(lrelu(y)) == exp2(max(x, 0.2x))
__device__ __forceinline__ float lrexp2(float x) {
  return exp2f(fmaxf(x, 0.2f * x));
}

// ------- K1: Wh1/Wh2 (transposed, f32) + s1/s2 (pre-scaled) + Z2 zero -------
__global__ __launch_bounds__(256) void k_prep(
    const float* __restrict__ h1, const float* __restrict__ h2,
    const float* __restrict__ W1, const float* __restrict__ W2,
    const float* __restrict__ a,
    float* __restrict__ Wh1T, float* __restrict__ Wh2T,
    float* __restrict__ s1, float* __restrict__ s2, float* __restrict__ Z2z) {
  __shared__ float hbuf[16][FIN];
  const int t = threadIdx.x;
  const int r0 = blockIdx.x * 16;
  const int f = t & 63, q = t >> 6;
  const int lrow = t >> 4, lc0 = (t & 15) * 16;
  {
    const int g = blockIdx.x * 256 + t;
    if (g < 2048)
      *(f32x4*)(Z2z + g * 4) = f32x4{0.f, 0.f, 0.f, 0.f};
  }
  for (int mat = 0; mat < 2; ++mat) {
    const float* h = mat ? h2 : h1;
    const float* W = mat ? W2 : W1;
    float* WhT = mat ? Wh2T : Wh1T;
    float* so = mat ? s2 : s1;
    const float av = a[mat * FOUT + f];
    __syncthreads();
    const float* src = h + (size_t)(r0 + lrow) * FIN + lc0;
#pragma unroll
    for (int u = 0; u < 4; ++u)
      *(f32x4*)&hbuf[lrow][lc0 + u * 4] = *(const f32x4*)(src + u * 4);
    __syncthreads();
    float acc[4] = {0.f, 0.f, 0.f, 0.f};
    for (int k = 0; k < FIN; ++k) {
      float wv = W[k * FOUT + f];
#pragma unroll
      for (int rg = 0; rg < 4; ++rg)
        acc[rg] = fmaf(hbuf[rg * 4 + q][k], wv, acc[rg]);
    }
#pragma unroll
    for (int rg = 0; rg < 4; ++rg) {
      int r = r0 + rg * 4 + q;
      WhT[(size_t)f * N + r] = acc[rg];
      float sp = acc[rg] * av;
#pragma unroll
      for (int m = 1; m < 64; m <<= 1) sp += __shfl_xor(sp, m, 64);
      if (f == 0) so[r] = sp * 1.4426950408889634f;  // fold log2(e)
    }
  }
}

// ---- K2: coalesced sign sweep -> bitmask (the only 256MB read) ----
// grid (8 col-stripes of 1024, 512 row-chunks of 16).
// Lane owns 4 CONSECUTIVE cols (16B/lane, 1KB/wave contiguous -- the r1
// pattern; r4-r8's 16-col/thread variant was a 64B-lane-stride sector killer).
// u16 words assembled via 4 shfls: lane L=(r=L>>4, w=L&15) gathers nibbles.
__global__ __launch_bounds__(256) void k_mask(const float* __restrict__ adj,
                                              u16* __restrict__ mask) {
  const int t = threadIdx.x;
  const int wv = t >> 6, ln = t & 63;
  const int sb = blockIdx.x * 1024;
  const int r0 = blockIdx.y * 16;
  const int c0 = sb + wv * 256 + ln * 4;
  const int r = ln >> 4, wl = ln & 15;
  const int srcb = wl * 4;
  u16* mbase = mask + (sb >> 4) + wv * 16 + wl;
#pragma unroll 1
  for (int g = 0; g < 4; ++g) {
    const int rr = r0 + g * 4;
    const f32x4 v0 = *(const f32x4*)(adj + (size_t)(rr + 0) * N + c0);
    const f32x4 v1 = *(const f32x4*)(adj + (size_t)(rr + 1) * N + c0);
    const f32x4 v2 = *(const f32x4*)(adj + (size_t)(rr + 2) * N + c0);
    const f32x4 v3 = *(const f32x4*)(adj + (size_t)(rr + 3) * N + c0);
    unsigned nibs = 0;
#pragma unroll
    for (int e = 0; e < 4; ++e) {
      nibs |= (v0[e] > 0.f ? 1u : 0u) << e;
      nibs |= (v1[e] > 0.f ? 1u : 0u) << (8 + e);
      nibs |= (v2[e] > 0.f ? 1u : 0u) << (16 + e);
      nibs |= (v3[e] > 0.f ? 1u : 0u) << (24 + e);
    }
    const unsigned n0 = __shfl(nibs, srcb + 0, 64);
    const unsigned n1 = __shfl(nibs, srcb + 1, 64);
    const unsigned n2 = __shfl(nibs, srcb + 2, 64);
    const unsigned n3 = __shfl(nibs, srcb + 3, 64);
    const int sh = 8 * r;
    const unsigned word = ((n0 >> sh) & 0xFu) | (((n1 >> sh) & 0xFu) << 4) |
                          (((n2 >> sh) & 0xFu) << 8) |
                          (((n3 >> sh) & 0xFu) << 12);
    mbase[(size_t)(rr + r) * 512] = (u16)word;
  }
}

// ------- K2b: Z1 row sums from mask (block per row, no atomics) -------
__global__ __launch_bounds__(256) void k_z1(const u16* __restrict__ maskp,
                                            const float* __restrict__ s1,
                                            const float* __restrict__ s2,
                                            float* __restrict__ Z1) {
  const int row = blockIdx.x;
  const int t = threadIdx.x, lane = t & 63, wv = t >> 6;
  const u64* mrow = (const u64*)maskp + (size_t)row * 128;
  const float s1v = s1[row];
  __shared__ float part[4];
  float z = 0.f;
#pragma unroll 2
  for (int k = 0; k < 32; ++k) {
    const u64 word = mrow[wv + 4 * k];  // wave-uniform -> broadcast
    const float s2v = s2[t + 256 * k];  // coalesced
    const float ev = lrexp2(s1v + s2v);
    z += ((word >> lane) & 1ull) ? ev : 0.f;
  }
#pragma unroll
  for (int sh = 1; sh < 64; sh <<= 1) z += __shfl_xor(z, sh, 64);
  if (lane == 0) part[wv] = z;
  __syncthreads();
  if (t == 0) Z1[row] = part[0] + part[1] + part[2] + part[3];
}

// ------- K2c: Z2 col sums from mask (thread per col, strip atomics) -------
__global__ __launch_bounds__(256) void k_z2(const u16* __restrict__ maskp,
                                            const float* __restrict__ s1,
                                            const float* __restrict__ s2,
                                            float* __restrict__ Z2) {
  const int j = blockIdx.x * 256 + threadIdx.x;
  const int i0 = blockIdx.y * 512;
  const int lane = threadIdx.x & 63;
  const u64* m64 = (const u64*)maskp + (j >> 6);
  const float s2v = s2[j];
  float z = 0.f;
#pragma unroll 2
  for (int i = i0; i < i0 + 512; ++i) {
    const u64 word = m64[(size_t)i * 128];  // wave-uniform -> broadcast
    const float ev = lrexp2(s1[i] + s2v);
    z += ((word >> lane) & 1ull) ? ev : 0.f;
  }
  atomicAdd(&Z2[j], z);
}

// ---------------- K3: V{1,2}T = (Wh/Z)^T in bf16 ----------------
__global__ __launch_bounds__(256) void k_buildv(
    const float* __restrict__ Wh1T, const float* __restrict__ Wh2T,
    const float* __restrict__ Z1, const float* __restrict__ Z2,
    u16* __restrict__ V1T, u16* __restrict__ V2T) {
  const int mat = blockIdx.y;
  const float* WhT = mat ? Wh2T : Wh1T;
  const float* Z = mat ? Z2 : Z1;
  u16* VT = mat ? V2T : V1T;
  const int idx = (blockIdx.x * 256 + threadIdx.x) * 4;
  const int i = idx & (N - 1);
  f32x4 wh = *(const f32x4*)(WhT + idx);
  f32x4 z = *(const f32x4*)(Z + i);
  unsigned lo = (unsigned)f2bf(wh.x / z.x) | ((unsigned)f2bf(wh.y / z.y) << 16);
  unsigned hi = (unsigned)f2bf(wh.z / z.z) | ((unsigned)f2bf(wh.w / z.w) << 16);
  uint2 uv; uv.x = lo; uv.y = hi;
  *(uint2*)(VT + idx) = uv;
}

// -- K4a: hp1 partial = E @ V2 over one j-strip. No atomics, plain stores. --
// grid (64 i-chunks of 128, NSTRIP j-strips of 512). Wave owns 32 rows.
__global__ __launch_bounds__(256, 2) void k_hp1(
    const u16* __restrict__ maskp, const float* __restrict__ s1g,
    const float* __restrict__ s2g, const u16* __restrict__ V2T,
    float* __restrict__ hp1P) {
  const int t = threadIdx.x, w = t >> 6, lane = t & 63;
  const int l15 = lane & 15, l4 = lane >> 4;
  const int sh0 = l4 * 8;
  const int i0 = blockIdx.x * 128 + w * 32;
  const int jbase = blockIdx.y * 512;
  const u64* mrow0 = (const u64*)maskp + (size_t)(i0 + l15) * 128;
  const u64* mrow1 = mrow0 + 16 * 128;
  const float s1v0 = s1g[i0 + l15];
  const float s1v1 = s1g[i0 + 16 + l15];
  f32x4 acc[2][4];
#pragma unroll
  for (int mt = 0; mt < 2; ++mt)
#pragma unroll
    for (int nt = 0; nt < 4; ++nt) acc[mt][nt] = f32x4{0.f, 0.f, 0.f, 0.f};

#pragma unroll 2
  for (int js = 0; js < 8; ++js) {
    const int j0s = jbase + js * 64;
    const u64 m0 = mrow0[j0s >> 6];
    const u64 m1 = mrow1[j0s >> 6];
    f32x4 s2q[4];  // [kk*2+h]: s2[j0s + kk*32 + sh0 + h*4 ..]
#pragma unroll
    for (int kk = 0; kk < 2; ++kk)
#pragma unroll
      for (int h = 0; h < 2; ++h)
        s2q[kk * 2 + h] = *(const f32x4*)(s2g + j0s + kk * 32 + sh0 + h * 4);
    s16x8 bf[2][4];
#pragma unroll
    for (int kk = 0; kk < 2; ++kk)
#pragma unroll
      for (int nt = 0; nt < 4; ++nt)
        bf[kk][nt] = *(const s16x8*)(V2T + (size_t)(nt * 16 + l15) * N + j0s +
                                     kk * 32 + sh0);
    s16x8 afr[2][2];  // [mt][kk]
#pragma unroll
    for (int kk = 0; kk < 2; ++kk) {
      const unsigned b0 = (unsigned)(kk ? (m0 >> 32) : m0);
      const unsigned b1 = (unsigned)(kk ? (m1 >> 32) : m1);
#pragma unroll
      for (int e = 0; e < 8; ++e) {
        const float s2e = s2q[kk * 2 + (e >> 2)][e & 3];
        float e0 = lrexp2(s1v0 + s2e);
        float e1 = lrexp2(s1v1 + s2e);
        e0 = ((b0 >> (sh0 + e)) & 1u) ? e0 : 0.f;
        e1 = ((b1 >> (sh0 + e)) & 1u) ? e1 : 0.f;
        afr[0][kk][e] = (short)f2bf_t(e0);
        afr[1][kk][e] = (short)f2bf_t(e1);
      }
    }
#pragma unroll
    for (int nt = 0; nt < 4; ++nt) {
      acc[0][nt] = __builtin_amdgcn_mfma_f32_16x16x32_bf16(afr[0][0], bf[0][nt],
                                                           acc[0][nt], 0, 0, 0);
      acc[0][nt] = __builtin_amdgcn_mfma_f32_16x16x32_bf16(afr[0][1], bf[1][nt],
                                                           acc[0][nt], 0, 0, 0);
      acc[1][nt] = __builtin_amdgcn_mfma_f32_16x16x32_bf16(afr[1][0], bf[0][nt],
                                                           acc[1][nt], 0, 0, 0);
      acc[1][nt] = __builtin_amdgcn_mfma_f32_16x16x32_bf16(afr[1][1], bf[1][nt],
                                                           acc[1][nt], 0, 0, 0);
    }
  }
  float* dst = hp1P + (size_t)blockIdx.y * HPSZ;
#pragma unroll
  for (int mt = 0; mt < 2; ++mt)
#pragma unroll
    for (int nt = 0; nt < 4; ++nt)
#pragma unroll
      for (int r = 0; r < 4; ++r)
        dst[(size_t)(i0 + mt * 16 + l4 * 4 + r) * 64 + nt * 16 + l15] =
            acc[mt][nt][r];
}

// -- K4b: hp2 partial = E^T @ V1 over one i-strip. No atomics. --
// grid (64 j-chunks of 128, NSTRIP i-strips of 512 = 8 tiles of 64).
__global__ __launch_bounds__(256, 2) void k_hp2(
    const u16* __restrict__ maskp, const float* __restrict__ s1g,
    const float* __restrict__ s2g, const u16* __restrict__ V1T,
    float* __restrict__ hp2P) {
  const int t = threadIdx.x, w = t >> 6, lane = t & 63;
  const int l15 = lane & 15, l4 = lane >> 4;
  const int sh0 = l4 * 8;
  const int j0w = blockIdx.x * 128 + w * 32;
  const int ibase = blockIdx.y * 512;
  const float s2vA = s2g[j0w + l15];
  const float s2vB = s2g[j0w + 16 + l15];
  const unsigned* mask32 = (const unsigned*)maskp;
  const int wsel = j0w >> 5;  // u32 index within a 256-word row
  f32x4 acc[2][4];
#pragma unroll
  for (int mt = 0; mt < 2; ++mt)
#pragma unroll
    for (int nt = 0; nt < 4; ++nt) acc[mt][nt] = f32x4{0.f, 0.f, 0.f, 0.f};

#pragma unroll 2
  for (int tile = 0; tile < 8; ++tile) {
    const int it0 = ibase + tile * 64;
    f32x4 s1q[4];
#pragma unroll
    for (int kk = 0; kk < 2; ++kk)
#pragma unroll
      for (int h = 0; h < 2; ++h)
        s1q[kk * 2 + h] = *(const f32x4*)(s1g + it0 + kk * 32 + sh0 + h * 4);
    unsigned mw[2][8];
#pragma unroll
    for (int kk = 0; kk < 2; ++kk)
#pragma unroll
      for (int e = 0; e < 8; ++e)
        mw[kk][e] = mask32[(size_t)(it0 + kk * 32 + sh0 + e) * 256 + wsel];
    s16x8 bf[2][4];
#pragma unroll
    for (int kk = 0; kk < 2; ++kk)
#pragma unroll
      for (int nt = 0; nt < 4; ++nt)
        bf[kk][nt] = *(const s16x8*)(V1T + (size_t)(nt * 16 + l15) * N + it0 +
                                     kk * 32 + sh0);
    s16x8 aA[2], aB[2];  // [kk] for mt=0 / mt=1
#pragma unroll
    for (int kk = 0; kk < 2; ++kk)
#pragma unroll
      for (int e = 0; e < 8; ++e) {
        const float s1v = s1q[kk * 2 + (e >> 2)][e & 3];
        float eA = lrexp2(s1v + s2vA);
        float eB = lrexp2(s1v + s2vB);
        const unsigned mwv = mw[kk][e];
        eA = ((mwv >> l15) & 1u) ? eA : 0.f;
        eB = ((mwv >> (16 + l15)) & 1u) ? eB : 0.f;
        aA[kk][e] = (short)f2bf_t(eA);
        aB[kk][e] = (short)f2bf_t(eB);
      }
#pragma unroll
    for (int nt = 0; nt < 4; ++nt) {
      acc[0][nt] = __builtin_amdgcn_mfma_f32_16x16x32_bf16(aA[0], bf[0][nt],
                                                           acc[0][nt], 0, 0, 0);
      acc[0][nt] = __builtin_amdgcn_mfma_f32_16x16x32_bf16(aA[1], bf[1][nt],
                                                           acc[0][nt], 0, 0, 0);
      acc[1][nt] = __builtin_amdgcn_mfma_f32_16x16x32_bf16(aB[0], bf[0][nt],
                                                           acc[1][nt], 0, 0, 0);
      acc[1][nt] = __builtin_amdgcn_mfma_f32_16x16x32_bf16(aB[1], bf[1][nt],
                                                           acc[1][nt], 0, 0, 0);
    }
  }
  float* dst = hp2P + (size_t)blockIdx.y * HPSZ;
#pragma unroll
  for (int mt = 0; mt < 2; ++mt)
#pragma unroll
    for (int nt = 0; nt < 4; ++nt)
#pragma unroll
      for (int r = 0; r < 4; ++r)
        dst[(size_t)(j0w + mt * 16 + l4 * 4 + r) * 64 + nt * 16 + l15] =
            acc[mt][nt][r];
}

// ------- K5: strip-sum + ELU epilogue for both outputs -------
__global__ __launch_bounds__(256) void k_red(const float* __restrict__ hp1P,
                                             const float* __restrict__ hp2P,
                                             float* __restrict__ out) {
  const size_t idx = ((size_t)blockIdx.x * 256 + threadIdx.x) * 4;
  f32x4 a1 = f32x4{0.f, 0.f, 0.f, 0.f};
  f32x4 a2 = f32x4{0.f, 0.f, 0.f, 0.f};
#pragma unroll 4
  for (int s = 0; s < NSTRIP; ++s) {
    a1 += *(const f32x4*)(hp1P + s * HPSZ + idx);
    a2 += *(const f32x4*)(hp2P + s * HPSZ + idx);
  }
  f32x4 o1, o2;
#pragma unroll
  for (int c = 0; c < 4; ++c) {
    o1[c] = a1[c] > 0.f ? a1[c] : expm1f(a1[c]);
    o2[c] = a2[c] > 0.f ? a2[c] : expm1f(a2[c]);
  }
  *(f32x4*)(out + idx) = o1;
  *(f32x4*)(out + (size_t)N * FOUT + idx) = o2;
}

extern "C" void kernel_launch(void* const* d_in, const int* in_sizes, int n_in,
                              void* d_out, int out_size, void* d_ws,
                              size_t ws_size, hipStream_t stream) {
  const float* h1 = (const float*)d_in[0];
  const float* h2 = (const float*)d_in[1];
  const float* adj = (const float*)d_in[2];
  const float* W1 = (const float*)d_in[3];
  const float* W2 = (const float*)d_in[4];
  const float* a = (const float*)d_in[5];

  float* ws = (float*)d_ws;
  // float-offset workspace layout (~82 MB total)
  float* s1 = ws + 0;
  float* s2 = ws + 8192;
  float* Z1 = ws + 16384;
  float* Z2 = ws + 24576;
  float* Wh1T = ws + 32768;               // [64][8192] f32
  float* Wh2T = ws + 557056;
  u16* V1T = (u16*)(ws + 1081344);        // [64][8192] bf16
  u16* V2T = V1T + 524288;
  u16* mask = (u16*)(ws + 1605632);       // [8192][512] u16 = 8 MB bitmask
  float* hp1P = ws + 3702784;             // [NSTRIP][8192][64] f32 = 32 MB
  float* hp2P = hp1P + NSTRIP * HPSZ;     // [NSTRIP][8192][64] f32 = 32 MB

  k_prep<<<512, 256, 0, stream>>>(h1, h2, W1, W2, a, Wh1T, Wh2T, s1, s2, Z2);
  k_mask<<<dim3(8, 512), 256, 0, stream>>>(adj, mask);
  k_z1<<<8192, 256, 0, stream>>>(mask, s1, s2, Z1);
  k_z2<<<dim3(32, 16), 256, 0, stream>>>(mask, s1, s2, Z2);
  k_buildv<<<dim3(512, 2), 256, 0, stream>>>(Wh1T, Wh2T, Z1, Z2, V1T, V2T);
  k_hp1<<<dim3(64, NSTRIP), 256, 0, stream>>>(mask, s1, s2, V2T, hp1P);
  k_hp2<<<dim3(64, NSTRIP), 256, 0, stream>>>(mask, s1, s2, V1T, hp2P);
  k_red<<<512, 256, 0, stream>>>(hp1P, hp2P, (float*)d_out);
}

// Round 10
// 307.895 us; speedup vs baseline: 2.2878x; 1.0705x over previous
//
#include <hip/hip_runtime.h>
#include <hip/hip_bf16.h>

// BGraphAttentionLayer: fused GAT layer, never materializes the 8192^2 attention.
// hp1 = E @ (Wh2/Z2), hp2 = E^T @ (Wh1/Z1), E = adj>0 ? exp(lrelu(s1_i+s2_j)) : 0.
// adj enters only via sign -> one pure-streaming coalesced sweep builds an 8MB
// bitmask; Z1/Z2 and the two MFMA sweeps recompute E from (mask, s1, s2).
// V matrices are pre-packed in MFMA-B-fragment order so every hp B-load is a
// fully coalesced 16B/lane load (the [64][8192] layout was a 16-way gather).
// hp outputs via split-K partials (plain stores) + strip-sum epilogue.
// s1/s2 are pre-scaled by log2(e) so E-gen uses exp2.

#define N 8192
#define FIN 256
#define FOUT 64
#define NSTRIP 8
#define HPSZ ((size_t)N * FOUT)  // 524288 floats per partial strip

typedef float f32x4 __attribute__((ext_vector_type(4)));
typedef short s16x8 __attribute__((ext_vector_type(8)));
typedef unsigned short u16;
typedef unsigned long long u64;

__device__ __forceinline__ u16 f2bf(float x) {
  unsigned u = __builtin_bit_cast(unsigned, x);
  return (u16)((u + 0x7FFFu + ((u >> 16) & 1u)) >> 16);  // RTNE
}
__device__ __forceinline__ u16 f2bf_t(float x) {  // truncating (cheap)
  return (u16)(__builtin_bit_cast(unsigned, x) >> 16);
}
// x is already scaled by log2(e): exp(lrelu(y)) == exp2(max(x, 0.2x))
__device__ __forceinline__ float lrexp2(float x) {
  return exp2f(fmaxf(x, 0.2f * x));
}

// ------- K1: Wh1/Wh2 (transposed, f32) + s1/s2 (pre-scaled) + Z2 zero -------
__global__ __launch_bounds__(256) void k_prep(
    const float* __restrict__ h1, const float* __restrict__ h2,
    const float* __restrict__ W1, const float* __restrict__ W2,
    const float* __restrict__ a,
    float* __restrict__ Wh1T, float* __restrict__ Wh2T,
    float* __restrict__ s1, float* __restrict__ s2, float* __restrict__ Z2z) {
  __shared__ float hbuf[16][FIN];
  const int t = threadIdx.x;
  const int r0 = blockIdx.x * 16;
  const int f = t & 63, q = t >> 6;
  const int lrow = t >> 4, lc0 = (t & 15) * 16;
  {
    const int g = blockIdx.x * 256 + t;
    if (g < 2048)
      *(f32x4*)(Z2z + g * 4) = f32x4{0.f, 0.f, 0.f, 0.f};
  }
  for (int mat = 0; mat < 2; ++mat) {
    const float* h = mat ? h2 : h1;
    const float* W = mat ? W2 : W1;
    float* WhT = mat ? Wh2T : Wh1T;
    float* so = mat ? s2 : s1;
    const float av = a[mat * FOUT + f];
    __syncthreads();
    const float* src = h + (size_t)(r0 + lrow) * FIN + lc0;
#pragma unroll
    for (int u = 0; u < 4; ++u)
      *(f32x4*)&hbuf[lrow][lc0 + u * 4] = *(const f32x4*)(src + u * 4);
    __syncthreads();
    float acc[4] = {0.f, 0.f, 0.f, 0.f};
    for (int k = 0; k < FIN; ++k) {
      float wv = W[k * FOUT + f];
#pragma unroll
      for (int rg = 0; rg < 4; ++rg)
        acc[rg] = fmaf(hbuf[rg * 4 + q][k], wv, acc[rg]);
    }
#pragma unroll
    for (int rg = 0; rg < 4; ++rg) {
      int r = r0 + rg * 4 + q;
      WhT[(size_t)f * N + r] = acc[rg];
      float sp = acc[rg] * av;
#pragma unroll
      for (int m = 1; m < 64; m <<= 1) sp += __shfl_xor(sp, m, 64);
      if (f == 0) so[r] = sp * 1.4426950408889634f;  // fold log2(e)
    }
  }
}

// ---- K2: coalesced sign sweep -> bitmask (the only 256MB read) ----
// grid (8 col-stripes of 1024, 256 row-chunks of 32). Lane owns 4 consecutive
// cols (16B/lane, 1KB/wave contiguous). u16 words assembled via 4 shfls.
__global__ __launch_bounds__(256) void k_mask(const float* __restrict__ adj,
                                              u16* __restrict__ mask) {
  const int t = threadIdx.x;
  const int wv = t >> 6, ln = t & 63;
  const int sb = blockIdx.x * 1024;
  const int r0 = blockIdx.y * 32;
  const int c0 = sb + wv * 256 + ln * 4;
  const int r = ln >> 4, wl = ln & 15;
  const int srcb = wl * 4;
  u16* mbase = mask + (sb >> 4) + wv * 16 + wl;
#pragma unroll 1
  for (int g = 0; g < 8; ++g) {
    const int rr = r0 + g * 4;
    const f32x4 v0 = *(const f32x4*)(adj + (size_t)(rr + 0) * N + c0);
    const f32x4 v1 = *(const f32x4*)(adj + (size_t)(rr + 1) * N + c0);
    const f32x4 v2 = *(const f32x4*)(adj + (size_t)(rr + 2) * N + c0);
    const f32x4 v3 = *(const f32x4*)(adj + (size_t)(rr + 3) * N + c0);
    unsigned nibs = 0;
#pragma unroll
    for (int e = 0; e < 4; ++e) {
      nibs |= (v0[e] > 0.f ? 1u : 0u) << e;
      nibs |= (v1[e] > 0.f ? 1u : 0u) << (8 + e);
      nibs |= (v2[e] > 0.f ? 1u : 0u) << (16 + e);
      nibs |= (v3[e] > 0.f ? 1u : 0u) << (24 + e);
    }
    const unsigned n0 = __shfl(nibs, srcb + 0, 64);
    const unsigned n1 = __shfl(nibs, srcb + 1, 64);
    const unsigned n2 = __shfl(nibs, srcb + 2, 64);
    const unsigned n3 = __shfl(nibs, srcb + 3, 64);
    const int sh = 8 * r;
    const unsigned word = ((n0 >> sh) & 0xFu) | (((n1 >> sh) & 0xFu) << 4) |
                          (((n2 >> sh) & 0xFu) << 8) |
                          (((n3 >> sh) & 0xFu) << 12);
    mbase[(size_t)(rr + r) * 512] = (u16)word;
  }
}

// ------- K2b: Z1 (blocks 0..2047, 4 rows each) + Z2 (blocks 2048..2559) -------
__global__ __launch_bounds__(256) void k_zboth(const u16* __restrict__ maskp,
                                               const float* __restrict__ s1,
                                               const float* __restrict__ s2,
                                               float* __restrict__ Z1,
                                               float* __restrict__ Z2) {
  const int t = threadIdx.x, lane = t & 63, wv = t >> 6;
  const int b = blockIdx.x;
  if (b < 2048) {
    // Z1: row sums, 4 rows per block, no atomics
    const int r0 = b * 4;
    __shared__ float part[4][4];
#pragma unroll 1
    for (int rr = 0; rr < 4; ++rr) {
      const int row = r0 + rr;
      const u64* mrow = (const u64*)maskp + (size_t)row * 128;
      const float s1v = s1[row];
      float z = 0.f;
#pragma unroll 2
      for (int k = 0; k < 32; ++k) {
        const u64 word = mrow[wv + 4 * k];  // wave-uniform -> broadcast
        const float s2v = s2[t + 256 * k];  // coalesced, L1-hot after rr=0
        const float ev = lrexp2(s1v + s2v);
        z += ((word >> lane) & 1ull) ? ev : 0.f;
      }
#pragma unroll
      for (int sh = 1; sh < 64; sh <<= 1) z += __shfl_xor(z, sh, 64);
      if (lane == 0) part[wv][rr] = z;
    }
    __syncthreads();
    if (t < 4)
      Z1[r0 + t] = part[0][t] + part[1][t] + part[2][t] + part[3][t];
  } else {
    // Z2: col sums, strip atomics (512 blocks)
    const int b2 = b - 2048;
    const int j = (b2 & 31) * 256 + t;
    const int i0 = (b2 >> 5) * 512;
    const u64* m64 = (const u64*)maskp + (j >> 6);
    const float s2v = s2[j];
    float z = 0.f;
#pragma unroll 2
    for (int i = i0; i < i0 + 512; ++i) {
      const u64 word = m64[(size_t)i * 128];  // wave-uniform -> broadcast
      const float ev = lrexp2(s1[i] + s2v);
      z += ((word >> lane) & 1ull) ? ev : 0.f;
    }
    atomicAdd(&Z2[j], z);
  }
}

// ---- K3: V{1,2}P = (Wh/Z) pre-packed in MFMA-B-fragment order (bf16) ----
// Fragment (jb, kk, nt, lane) holds 8 consecutive u16: element e is
// Wh[f = nt*16 + (lane&15)][j = jb*64 + kk*32 + (lane>>4)*8 + e] / Z[j].
// Output address = g*8 u16 where g = ((jb*2+kk)*4+nt)*64 + lane.
__global__ __launch_bounds__(256) void k_buildv(
    const float* __restrict__ Wh1T, const float* __restrict__ Wh2T,
    const float* __restrict__ Z1, const float* __restrict__ Z2,
    u16* __restrict__ V1P, u16* __restrict__ V2P) {
  const int mat = blockIdx.y;
  const float* WhT = mat ? Wh2T : Wh1T;
  const float* Z = mat ? Z2 : Z1;
  u16* VP = mat ? V2P : V1P;
  const int g = blockIdx.x * 256 + threadIdx.x;
  const int lane = g & 63, nt = (g >> 6) & 3, kk = (g >> 8) & 1, jb = g >> 9;
  const int j = jb * 64 + kk * 32 + (lane >> 4) * 8;
  const int f = nt * 16 + (lane & 15);
  const float* src = WhT + (size_t)f * N + j;
  const f32x4 wa = *(const f32x4*)(src);
  const f32x4 wb = *(const f32x4*)(src + 4);
  const f32x4 za = *(const f32x4*)(Z + j);
  const f32x4 zb = *(const f32x4*)(Z + j + 4);
  uint4 o;
  o.x = (unsigned)f2bf(wa.x / za.x) | ((unsigned)f2bf(wa.y / za.y) << 16);
  o.y = (unsigned)f2bf(wa.z / za.z) | ((unsigned)f2bf(wa.w / za.w) << 16);
  o.z = (unsigned)f2bf(wb.x / zb.x) | ((unsigned)f2bf(wb.y / zb.y) << 16);
  o.w = (unsigned)f2bf(wb.z / zb.z) | ((unsigned)f2bf(wb.w / zb.w) << 16);
  *(uint4*)(VP + (size_t)g * 8) = o;
}

// -- K4: merged hp kernels. z=0: hp1 partial = E@V2 over j-strip.
//        z=1: hp2 partial = E^T@V1 over i-strip. Plain stores, no atomics.
// grid (64 chunks of 128, NSTRIP strips of 1024, 2).
__global__ __launch_bounds__(256, 2) void k_hp(
    const u16* __restrict__ maskp, const float* __restrict__ s1g,
    const float* __restrict__ s2g, const u16* __restrict__ V1P,
    const u16* __restrict__ V2P, float* __restrict__ hp1P,
    float* __restrict__ hp2P) {
  const int t = threadIdx.x, w = t >> 6, lane = t & 63;
  const int l15 = lane & 15, l4 = lane >> 4;
  const int sh0 = l4 * 8;
  f32x4 acc[2][4];
#pragma unroll
  for (int mt = 0; mt < 2; ++mt)
#pragma unroll
    for (int nt = 0; nt < 4; ++nt) acc[mt][nt] = f32x4{0.f, 0.f, 0.f, 0.f};

  if (blockIdx.z == 0) {
    // ---------------- hp1: rows i, K-axis j ----------------
    const int i0 = blockIdx.x * 128 + w * 32;
    const int jbase = blockIdx.y * 1024;
    const u64* mrow0 = (const u64*)maskp + (size_t)(i0 + l15) * 128;
    const u64* mrow1 = mrow0 + 16 * 128;
    const float s1v0 = s1g[i0 + l15];
    const float s1v1 = s1g[i0 + 16 + l15];
#pragma unroll 2
    for (int js = 0; js < 16; ++js) {
      const int j0s = jbase + js * 64;
      const u64 m0 = mrow0[j0s >> 6];
      const u64 m1 = mrow1[j0s >> 6];
      f32x4 s2q[4];
#pragma unroll
      for (int kk = 0; kk < 2; ++kk)
#pragma unroll
        for (int h = 0; h < 2; ++h)
          s2q[kk * 2 + h] = *(const f32x4*)(s2g + j0s + kk * 32 + sh0 + h * 4);
      s16x8 afr[2][2];  // [mt][kk]
#pragma unroll
      for (int kk = 0; kk < 2; ++kk) {
        const unsigned b0 = (unsigned)(kk ? (m0 >> 32) : m0);
        const unsigned b1 = (unsigned)(kk ? (m1 >> 32) : m1);
#pragma unroll
        for (int e = 0; e < 8; ++e) {
          const float s2e = s2q[kk * 2 + (e >> 2)][e & 3];
          float e0 = lrexp2(s1v0 + s2e);
          float e1 = lrexp2(s1v1 + s2e);
          e0 = ((b0 >> (sh0 + e)) & 1u) ? e0 : 0.f;
          e1 = ((b1 >> (sh0 + e)) & 1u) ? e1 : 0.f;
          afr[0][kk][e] = (short)f2bf_t(e0);
          afr[1][kk][e] = (short)f2bf_t(e1);
        }
      }
      const u16* vb = V2P + (((size_t)(j0s >> 6) * 8) << 9) + lane * 8;
#pragma unroll
      for (int half = 0; half < 2; ++half) {
        const int n0 = half * 2, n1 = half * 2 + 1;
        const s16x8 bf00 = *(const s16x8*)(vb + ((0 * 4 + n0) << 9));
        const s16x8 bf01 = *(const s16x8*)(vb + ((0 * 4 + n1) << 9));
        const s16x8 bf10 = *(const s16x8*)(vb + ((1 * 4 + n0) << 9));
        const s16x8 bf11 = *(const s16x8*)(vb + ((1 * 4 + n1) << 9));
        acc[0][n0] = __builtin_amdgcn_mfma_f32_16x16x32_bf16(afr[0][0], bf00,
                                                             acc[0][n0], 0, 0, 0);
        acc[0][n0] = __builtin_amdgcn_mfma_f32_16x16x32_bf16(afr[0][1], bf10,
                                                             acc[0][n0], 0, 0, 0);
        acc[0][n1] = __builtin_amdgcn_mfma_f32_16x16x32_bf16(afr[0][0], bf01,
                                                             acc[0][n1], 0, 0, 0);
        acc[0][n1] = __builtin_amdgcn_mfma_f32_16x16x32_bf16(afr[0][1], bf11,
                                                             acc[0][n1], 0, 0, 0);
        acc[1][n0] = __builtin_amdgcn_mfma_f32_16x16x32_bf16(afr[1][0], bf00,
                                                             acc[1][n0], 0, 0, 0);
        acc[1][n0] = __builtin_amdgcn_mfma_f32_16x16x32_bf16(afr[1][1], bf10,
                                                             acc[1][n0], 0, 0, 0);
        acc[1][n1] = __builtin_amdgcn_mfma_f32_16x16x32_bf16(afr[1][0], bf01,
                                                             acc[1][n1], 0, 0, 0);
        acc[1][n1] = __builtin_amdgcn_mfma_f32_16x16x32_bf16(afr[1][1], bf11,
                                                             acc[1][n1], 0, 0, 0);
      }
    }
    float* dst = hp1P + (size_t)blockIdx.y * HPSZ;
#pragma unroll
    for (int mt = 0; mt < 2; ++mt)
#pragma unroll
      for (int nt = 0; nt < 4; ++nt)
#pragma unroll
        for (int r = 0; r < 4; ++r)
          dst[(size_t)(i0 + mt * 16 + l4 * 4 + r) * 64 + nt * 16 + l15] =
              acc[mt][nt][r];
  } else {
    // ---------------- hp2: rows j, K-axis i ----------------
    const int j0w = blockIdx.x * 128 + w * 32;
    const int ibase = blockIdx.y * 1024;
    const float s2vA = s2g[j0w + l15];
    const float s2vB = s2g[j0w + 16 + l15];
    const unsigned* mask32 = (const unsigned*)maskp;
    const int wsel = j0w >> 5;
#pragma unroll 2
    for (int tile = 0; tile < 16; ++tile) {
      const int it0 = ibase + tile * 64;
      f32x4 s1q[4];
#pragma unroll
      for (int kk = 0; kk < 2; ++kk)
#pragma unroll
        for (int h = 0; h < 2; ++h)
          s1q[kk * 2 + h] = *(const f32x4*)(s1g + it0 + kk * 32 + sh0 + h * 4);
      unsigned mw[2][8];
#pragma unroll
      for (int kk = 0; kk < 2; ++kk)
#pragma unroll
        for (int e = 0; e < 8; ++e)
          mw[kk][e] = mask32[(size_t)(it0 + kk * 32 + sh0 + e) * 256 + wsel];
      s16x8 aA[2], aB[2];
#pragma unroll
      for (int kk = 0; kk < 2; ++kk)
#pragma unroll
        for (int e = 0; e < 8; ++e) {
          const float s1v = s1q[kk * 2 + (e >> 2)][e & 3];
          float eA = lrexp2(s1v + s2vA);
          float eB = lrexp2(s1v + s2vB);
          const unsigned mwv = mw[kk][e];
          eA = ((mwv >> l15) & 1u) ? eA : 0.f;
          eB = ((mwv >> (16 + l15)) & 1u) ? eB : 0.f;
          aA[kk][e] = (short)f2bf_t(eA);
          aB[kk][e] = (short)f2bf_t(eB);
        }
      const u16* vb = V1P + (((size_t)(it0 >> 6) * 8) << 9) + lane * 8;
#pragma unroll
      for (int half = 0; half < 2; ++half) {
        const int n0 = half * 2, n1 = half * 2 + 1;
        const s16x8 bf00 = *(const s16x8*)(vb + ((0 * 4 + n0) << 9));
        const s16x8 bf01 = *(const s16x8*)(vb + ((0 * 4 + n1) << 9));
        const s16x8 bf10 = *(const s16x8*)(vb + ((1 * 4 + n0) << 9));
        const s16x8 bf11 = *(const s16x8*)(vb + ((1 * 4 + n1) << 9));
        acc[0][n0] = __builtin_amdgcn_mfma_f32_16x16x32_bf16(aA[0], bf00,
                                                             acc[0][n0], 0, 0, 0);
        acc[0][n0] = __builtin_amdgcn_mfma_f32_16x16x32_bf16(aA[1], bf10,
                                                             acc[0][n0], 0, 0, 0);
        acc[0][n1] = __builtin_amdgcn_mfma_f32_16x16x32_bf16(aA[0], bf01,
                                                             acc[0][n1], 0, 0, 0);
        acc[0][n1] = __builtin_amdgcn_mfma_f32_16x16x32_bf16(aA[1], bf11,
                                                             acc[0][n1], 0, 0, 0);
        acc[1][n0] = __builtin_amdgcn_mfma_f32_16x16x32_bf16(aB[0], bf00,
                                                             acc[1][n0], 0, 0, 0);
        acc[1][n0] = __builtin_amdgcn_mfma_f32_16x16x32_bf16(aB[1], bf10,
                                                             acc[1][n0], 0, 0, 0);
        acc[1][n1] = __builtin_amdgcn_mfma_f32_16x16x32_bf16(aB[0], bf01,
                                                             acc[1][n1], 0, 0, 0);
        acc[1][n1] = __builtin_amdgcn_mfma_f32_16x16x32_bf16(aB[1], bf11,
                                                             acc[1][n1], 0, 0, 0);
      }
    }
    float* dst = hp2P + (size_t)blockIdx.y * HPSZ;
#pragma unroll
    for (int mt = 0; mt < 2; ++mt)
#pragma unroll
      for (int nt = 0; nt < 4; ++nt)
#pragma unroll
        for (int r = 0; r < 4; ++r)
          dst[(size_t)(j0w + mt * 16 + l4 * 4 + r) * 64 + nt * 16 + l15] =
              acc[mt][nt][r];
  }
}

// ------- K5: strip-sum + ELU epilogue for both outputs -------
__global__ __launch_bounds__(256) void k_red(const float* __restrict__ hp1P,
                                             const float* __restrict__ hp2P,
                                             float* __restrict__ out) {
  const size_t idx = ((size_t)blockIdx.x * 256 + threadIdx.x) * 4;
  f32x4 a1 = f32x4{0.f, 0.f, 0.f, 0.f};
  f32x4 a2 = f32x4{0.f, 0.f, 0.f, 0.f};
#pragma unroll 4
  for (int s = 0; s < NSTRIP; ++s) {
    a1 += *(const f32x4*)(hp1P + s * HPSZ + idx);
    a2 += *(const f32x4*)(hp2P + s * HPSZ + idx);
  }
  f32x4 o1, o2;
#pragma unroll
  for (int c = 0; c < 4; ++c) {
    o1[c] = a1[c] > 0.f ? a1[c] : expm1f(a1[c]);
    o2[c] = a2[c] > 0.f ? a2[c] : expm1f(a2[c]);
  }
  *(f32x4*)(out + idx) = o1;
  *(f32x4*)(out + (size_t)N * FOUT + idx) = o2;
}

extern "C" void kernel_launch(void* const* d_in, const int* in_sizes, int n_in,
                              void* d_out, int out_size, void* d_ws,
                              size_t ws_size, hipStream_t stream) {
  const float* h1 = (const float*)d_in[0];
  const float* h2 = (const float*)d_in[1];
  const float* adj = (const float*)d_in[2];
  const float* W1 = (const float*)d_in[3];
  const float* W2 = (const float*)d_in[4];
  const float* a = (const float*)d_in[5];

  float* ws = (float*)d_ws;
  // float-offset workspace layout (~48 MB total)
  float* s1 = ws + 0;
  float* s2 = ws + 8192;
  float* Z1 = ws + 16384;
  float* Z2 = ws + 24576;
  float* Wh1T = ws + 32768;               // [64][8192] f32
  float* Wh2T = ws + 557056;
  u16* V1P = (u16*)(ws + 1081344);        // fragment-packed bf16, 1 MB
  u16* V2P = (u16*)(ws + 1343488);
  u16* mask = (u16*)(ws + 1605632);       // [8192][512] u16 = 8 MB bitmask
  float* hp1P = ws + 3702784;             // [NSTRIP][8192][64] f32 = 16 MB
  float* hp2P = hp1P + NSTRIP * HPSZ;     // [NSTRIP][8192][64] f32 = 16 MB

  k_prep<<<512, 256, 0, stream>>>(h1, h2, W1, W2, a, Wh1T, Wh2T, s1, s2, Z2);
  k_mask<<<dim3(8, 256), 256, 0, stream>>>(adj, mask);
  k_zboth<<<2560, 256, 0, stream>>>(mask, s1, s2, Z1, Z2);
  k_buildv<<<dim3(256, 2), 256, 0, stream>>>(Wh1T, Wh2T, Z1, Z2, V1P, V2P);
  k_hp<<<dim3(64, NSTRIP, 2), 256, 0, stream>>>(mask, s1, s2, V1P, V2P, hp1P,
                                                hp2P);
  k_red<<<512, 256, 0, stream>>>(hp1P, hp2P, (float*)d_out);
}